// Round 10
// baseline (91.023 us; speedup 1.0000x reference)
//
#include <hip/hip_runtime.h>
#include <stdint.h>

#define NSEQ   1536
#define NBATCH 4
#define NM     (NBATCH * NSEQ)   // 6144
#define DMODEL 512
#define NHEAD  8
#define HD     64
#define TBLN   2047              // 2*1024-1

typedef __attribute__((ext_vector_type(4))) float  f32x4;
typedef __attribute__((ext_vector_type(4))) int    i32x4;
typedef __attribute__((ext_vector_type(8))) __bf16 bf16x8;
typedef unsigned short u16;

static_assert(sizeof(bf16x8) == 16, "bf16x8 must be 16B");

__device__ inline u16 f2bf(float f) {
  union { float f; uint32_t u; } v; v.f = f;
  uint32_t u = v.u;
  return (u16)((u + 0x7fffu + ((u >> 16) & 1u)) >> 16);   // RNE
}

__device__ inline bf16x8 ld_bf8(const u16* p) {
  i32x4 v = *(const i32x4*)p;
  return __builtin_bit_cast(bf16x8, v);
}

__device__ inline f32x4 mfma16(bf16x8 a, bf16x8 b, f32x4 c) {
  return __builtin_amdgcn_mfma_f32_16x16x32_bf16(a, b, c, 0, 0, 0);
}

__device__ inline void gload_lds16(const void* g, void* l) {
  __builtin_amdgcn_global_load_lds(
      (__attribute__((address_space(1))) void*)(g),
      (__attribute__((address_space(3))) void*)(l), 16, 0, 0);
}

__device__ inline uint32_t pkbf(float a, float b) {
  uint32_t r;
  asm("v_cvt_pk_bf16_f32 %0, %1, %2" : "=v"(r) : "v"(a), "v"(b));
  return r;   // lo16 = bf16(a), hi16 = bf16(b)
}

__device__ inline float exp2_raw(float x) {   // |x| small: no libm guards
  float r;
  asm("v_exp_f32 %0, %1" : "=v"(r) : "v"(x));
  return r;
}

__device__ inline float bfhi(uint32_t u) {    // high bf16 -> f32
  union { uint32_t u; float f; } v; v.u = u & 0xffff0000u; return v.f;
}
__device__ inline float bflo(uint32_t u) {    // low bf16 -> f32
  union { uint32_t u; float f; } v; v.u = u << 16; return v.f;
}

// ---------------------------------------------------------------- LayerNorm
__global__ __launch_bounds__(256) void ln_kernel(
    const float* __restrict__ vis, const float* __restrict__ txt,
    const float* __restrict__ gamma, const float* __restrict__ beta,
    u16* __restrict__ zn) {
  const int lane = threadIdx.x & 63;
  const int row  = blockIdx.x * 4 + (threadIdx.x >> 6);
  const int b = row / NSEQ, n = row - b * NSEQ;
  const float* src = (n < 1024) ? (vis + ((size_t)b * 1024 + n) * DMODEL)
                                : (txt + ((size_t)b * 512 + (n - 1024)) * DMODEL);
  const float4* s4 = (const float4*)src;
  float4 x0 = s4[lane], x1 = s4[lane + 64];
  float s = x0.x + x0.y + x0.z + x0.w + x1.x + x1.y + x1.z + x1.w;
  float q = x0.x*x0.x + x0.y*x0.y + x0.z*x0.z + x0.w*x0.w
          + x1.x*x1.x + x1.y*x1.y + x1.z*x1.z + x1.w*x1.w;
  #pragma unroll
  for (int m = 1; m < 64; m <<= 1) { s += __shfl_xor(s, m); q += __shfl_xor(q, m); }
  const float mean = s * (1.0f / 512.0f);
  const float var  = q * (1.0f / 512.0f) - mean * mean;
  const float rstd = rsqrtf(var + 1e-5f);
  const float4* g4 = (const float4*)gamma;
  const float4* b4 = (const float4*)beta;
  float4 g0 = g4[lane], g1 = g4[lane + 64], p0 = b4[lane], p1 = b4[lane + 64];
  u16* dst = zn + (size_t)row * DMODEL;
  ushort4 o0, o1;
  o0.x = f2bf((x0.x - mean) * rstd * g0.x + p0.x);
  o0.y = f2bf((x0.y - mean) * rstd * g0.y + p0.y);
  o0.z = f2bf((x0.z - mean) * rstd * g0.z + p0.z);
  o0.w = f2bf((x0.w - mean) * rstd * g0.w + p0.w);
  o1.x = f2bf((x1.x - mean) * rstd * g1.x + p1.x);
  o1.y = f2bf((x1.y - mean) * rstd * g1.y + p1.y);
  o1.z = f2bf((x1.z - mean) * rstd * g1.z + p1.z);
  o1.w = f2bf((x1.w - mean) * rstd * g1.w + p1.w);
  *(ushort4*)(dst + lane * 4)        = o0;
  *(ushort4*)(dst + (lane + 64) * 4) = o1;
}

// ------------------------------------------------- weight transpose -> bf16
__global__ __launch_bounds__(256) void wtrans_kernel(
    const float* __restrict__ WQ, const float* __restrict__ WK,
    const float* __restrict__ WV, const float* __restrict__ WO,
    u16* __restrict__ wqkvt, u16* __restrict__ wot) {
  __shared__ float t[32][33];
  const int m = blockIdx.z;
  const float* W = (m == 0) ? WQ : (m == 1) ? WK : (m == 2) ? WV : WO;
  const int n0 = blockIdx.x * 32, k0 = blockIdx.y * 32;
  const int tx = threadIdx.x & 31, ty = threadIdx.x >> 5;
  #pragma unroll
  for (int j = 0; j < 4; ++j)
    t[ty + j * 8][tx] = W[(size_t)(k0 + ty + j * 8) * DMODEL + n0 + tx];
  __syncthreads();
  u16* out = (m < 3) ? (wqkvt + (size_t)m * DMODEL * DMODEL) : wot;
  #pragma unroll
  for (int j = 0; j < 4; ++j)
    out[(size_t)(n0 + ty + j * 8) * DMODEL + k0 + tx] = f2bf(t[tx][ty + j * 8]);
}

// ------------------------------------------------------------- QKV GEMM
// 128(M) x 96(N) tile, BK=64, 4 waves (2x2), wave tile 64x48.
// grid 16x48 = 768 blocks = exactly 3 per CU (balanced).
__global__ __launch_bounds__(256) void gemm_qkv(
    const u16* __restrict__ A, const u16* __restrict__ Bt,
    const float* __restrict__ bQ, const float* __restrict__ bK, const float* __restrict__ bV,
    u16* __restrict__ Q, u16* __restrict__ Kk, u16* __restrict__ Vt) {
  __shared__ __align__(16) u16 lat[128 * 64];
  __shared__ __align__(16) u16 lbt[96 * 64];
  const int tid = threadIdx.x, lane = tid & 63, w = tid >> 6;
  const int wr = w >> 1, wc = w & 1;
  const int m0 = blockIdx.y * 128, n0 = blockIdx.x * 96;
  f32x4 acc[4][3] = {};
  for (int kt = 0; kt < 8; ++kt) {
    const int k0 = kt * 64;
    #pragma unroll
    for (int i = 0; i < 4; ++i) {
      int ch = tid + 256 * i;                 // A: 1024 chunks
      int row = ch >> 3, pc = ch & 7;
      int kk = k0 + ((pc ^ (row & 7)) << 3);
      gload_lds16(A + (size_t)(m0 + row) * DMODEL + kk, lat + (size_t)ch * 8);
    }
    #pragma unroll
    for (int i = 0; i < 3; ++i) {
      int ch = tid + 256 * i;                 // B: 768 chunks
      int row = ch >> 3, pc = ch & 7;
      int kk = k0 + ((pc ^ (row & 7)) << 3);
      gload_lds16(Bt + (size_t)(n0 + row) * DMODEL + kk, lbt + (size_t)ch * 8);
    }
    __syncthreads();
    #pragma unroll
    for (int ks = 0; ks < 2; ++ks) {
      bf16x8 af[4], bfr[3];
      const int cc = ks * 4 + (lane >> 4);
      #pragma unroll
      for (int f = 0; f < 4; ++f) {
        int ra = wr * 64 + f * 16 + (lane & 15);
        af[f]  = ld_bf8(lat + ra * 64 + ((cc ^ (ra & 7)) << 3));
      }
      #pragma unroll
      for (int f = 0; f < 3; ++f) {
        int rb = wc * 48 + f * 16 + (lane & 15);
        bfr[f] = ld_bf8(lbt + rb * 64 + ((cc ^ (rb & 7)) << 3));
      }
      #pragma unroll
      for (int fr = 0; fr < 4; ++fr)
        #pragma unroll
        for (int fc = 0; fc < 3; ++fc)
          acc[fr][fc] = mfma16(af[fr], bfr[fc], acc[fr][fc]);
    }
    __syncthreads();
  }
  #pragma unroll
  for (int fr = 0; fr < 4; ++fr) {
    const int mbase = m0 + wr * 64 + fr * 16 + ((lane >> 4) << 2);
    const int b = mbase / NSEQ;
    const int nseq = mbase - b * NSEQ;
    #pragma unroll
    for (int fc = 0; fc < 3; ++fc) {
      const int col = n0 + wc * 48 + fc * 16 + (lane & 15);
      const int which = col >> 9;
      const int cw = col & 511;
      const int h = cw >> 6, d = cw & 63;
      const float bias = (which == 0) ? bQ[cw] : (which == 1) ? bK[cw] : bV[cw];
      if (which < 2) {
        u16* dst = ((which == 0) ? Q : Kk) + ((size_t)(b * NHEAD + h) * NSEQ + nseq) * HD + d;
        #pragma unroll
        for (int r = 0; r < 4; ++r) dst[(size_t)r * HD] = f2bf(acc[fr][fc][r] + bias);
      } else {
        ushort4 pv;
        pv.x = f2bf(acc[fr][fc][0] + bias);
        pv.y = f2bf(acc[fr][fc][1] + bias);
        pv.z = f2bf(acc[fr][fc][2] + bias);
        pv.w = f2bf(acc[fr][fc][3] + bias);
        *(ushort4*)(Vt + ((size_t)(b * NHEAD + h) * HD + d) * NSEQ + nseq) = pv;
      }
    }
  }
}

// ------------------------------------------------------------ O-proj GEMM
// 64x64 tile, 4 waves (2x2), wave tile 32x32. grid 8x96 = 768 blocks (3/CU).
__global__ __launch_bounds__(256) void gemm_oproj(
    const u16* __restrict__ A, const u16* __restrict__ Bt,
    const float* __restrict__ bO, float* __restrict__ out) {
  __shared__ __align__(16) u16 lat[64 * 64];
  __shared__ __align__(16) u16 lbt[64 * 64];
  const int tid = threadIdx.x, lane = tid & 63, w = tid >> 6;
  const int wr = w >> 1, wc = w & 1;
  const int m0 = blockIdx.y * 64, n0 = blockIdx.x * 64;
  f32x4 acc[2][2] = {};
  for (int kt = 0; kt < 8; ++kt) {
    const int k0 = kt * 64;
    #pragma unroll
    for (int i = 0; i < 2; ++i) {
      int ch = tid + 256 * i;                 // 512 chunks each
      int row = ch >> 3, pc = ch & 7;
      int kk = k0 + ((pc ^ (row & 7)) << 3);
      gload_lds16(A  + (size_t)(m0 + row) * DMODEL + kk, lat + (size_t)ch * 8);
      gload_lds16(Bt + (size_t)(n0 + row) * DMODEL + kk, lbt + (size_t)ch * 8);
    }
    __syncthreads();
    #pragma unroll
    for (int ks = 0; ks < 2; ++ks) {
      bf16x8 af[2], bfr[2];
      const int cc = ks * 4 + (lane >> 4);
      #pragma unroll
      for (int f = 0; f < 2; ++f) {
        int ra = wr * 32 + f * 16 + (lane & 15);
        af[f]  = ld_bf8(lat + ra * 64 + ((cc ^ (ra & 7)) << 3));
        int rb = wc * 32 + f * 16 + (lane & 15);
        bfr[f] = ld_bf8(lbt + rb * 64 + ((cc ^ (rb & 7)) << 3));
      }
      #pragma unroll
      for (int fr = 0; fr < 2; ++fr)
        #pragma unroll
        for (int fc = 0; fc < 2; ++fc)
          acc[fr][fc] = mfma16(af[fr], bfr[fc], acc[fr][fc]);
    }
    __syncthreads();
  }
  #pragma unroll
  for (int fr = 0; fr < 2; ++fr) {
    const int mbase = m0 + wr * 32 + fr * 16 + ((lane >> 4) << 2);
    #pragma unroll
    for (int fc = 0; fc < 2; ++fc) {
      const int col = n0 + wc * 32 + fc * 16 + (lane & 15);
      const float bias = bO[col];
      float* dst = out + (size_t)mbase * DMODEL + col;
      #pragma unroll
      for (int r = 0; r < 4; ++r) dst[(size_t)r * DMODEL] = acc[fr][fc][r] + bias;
    }
  }
}

// ------------------------------------------------------------ attention v10
// LDS-traffic cut: 4 waves x 48 q (3 subtiles, K/V frag feeds 3 MFMA), bf16
// bias (even/odd copies, one aligned 8B read per 4 values). 68 KB LDS ->
// 2 blocks/CU. Sync = v9-validated dbuf + two arrival barriers + counted
// vmcnt(4), at 64k granularity. Swapped QK^T, no-max exp2 softmax.
__global__ __launch_bounds__(256, 2) void attn_kernel(
    const u16* __restrict__ Q, const u16* __restrict__ K,
    const u16* __restrict__ Vt, const float* __restrict__ table,
    u16* __restrict__ O) {
  __shared__ u16 rb2[2][3072];                    // 12 KB bf16 bias*log2e, copies c: rb2[c][x]=rev[x+c]
  __shared__ __align__(16) u16 kbuf[2][4096];     // 16 KB (64k x 64d)
  __shared__ __align__(16) u16 vbuf[2][4096];     // 16 KB (64d x 64k)
  __shared__ __align__(16) u16 plds[4][3][1024];  // 24 KB wave-private P (3 subtiles)
  const int tid = threadIdx.x, lane = tid & 63, w = tid >> 6;
  const int bid = blockIdx.x;
  const int xcd = bid & 7, idx = bid >> 3;        // idx in [0,32)
  const int bh  = xcd * 4 + (idx & 3);
  const int qt  = idx >> 2;                       // [0,8)
  const int h   = bh & (NHEAD - 1);
  // rev[t] = bf16(table[clamp(2558-t,0,2046)][h] * log2e); rb2[c][x] = rev[x+c]
  for (int t = tid; t < 2 * 3072; t += 256) {
    const int c = (t >= 3072) ? 1 : 0;
    const int x = t - c * 3072;
    int src = 2558 - (x + c);
    src = src < 0 ? 0 : (src > 2046 ? 2046 : src);
    rb2[c][x] = f2bf(table[(size_t)src * NHEAD + h] * 1.4426950408889634f);
  }

  const int lo16 = lane & 15, g = lane >> 4;
  const int q0 = qt * 192 + w * 48;
  const u16* Qb = Q  + (size_t)bh * NSEQ * HD;
  const u16* Kb = K  + (size_t)bh * NSEQ * HD;
  const u16* Vb = Vt + (size_t)bh * HD * NSEQ;

  // staging: all 256 threads, 4 gload each (2 K + 2 V) per 64k tile.
#define STAGE(buf, k0)                                                        \
  do {                                                                        \
    _Pragma("unroll")                                                         \
    for (int i = 0; i < 2; ++i) {                                             \
      int ch = tid + 256 * i;                                                 \
      int row = ch >> 3, pc = ch & 7;                                         \
      int col = (pc ^ (row & 7)) << 3;                                        \
      gload_lds16(Kb + (size_t)((k0) + row) * HD + col, kbuf[buf] + (size_t)ch * 8); \
      gload_lds16(Vb + (size_t)row * NSEQ + (k0) + col, vbuf[buf] + (size_t)ch * 8); \
    }                                                                         \
  } while (0)

  bf16x8 qf[3][2];
  #pragma unroll
  for (int s = 0; s < 3; ++s)
    #pragma unroll
    for (int kd = 0; kd < 2; ++kd)
      qf[s][kd] = ld_bf8(Qb + (size_t)(q0 + s * 16 + lo16) * HD + kd * 32 + g * 8);

  float l_part[3] = {0.f, 0.f, 0.f};
  f32x4 acc[3][4] = {};

  const int pswz  = (lo16 & 7) << 4;
  const int wbase = lo16 * 128;
  const int rswz  = lo16 & 7;
  // bias: value(s,kc,r) = rev[B + k0 + 16*(kc - s + 2) + r], B in [0,1515]
  const int B   = 1535 - q0 - lo16 + 4 * g - 32;
  const int c2  = B & 1;
  const int dwb = (B - c2) >> 1;                  // dword base into rb2[c2]
  const uint32_t* rbp32 = (const uint32_t*)rb2[c2];
  const float c1 = 0.125f * 1.4426950408889634f;  // scale * log2(e)

  STAGE(0, 0);
  __syncthreads();                       // bias writes + stage0 drain
  int cur = 0;

  for (int kt = 0; kt < 24; ++kt) {
    const int k0 = kt * 64;
    const int nxt = cur ^ 1;
    if (kt < 23) {
      STAGE(nxt, k0 + 64);
      asm volatile("s_waitcnt vmcnt(4)" ::: "memory");
    } else {
      asm volatile("s_waitcnt vmcnt(0)" ::: "memory");
    }
    __builtin_amdgcn_s_barrier();        // stage(kt) visible; stage(kt+1) in flight
    const u16* kb = kbuf[cur];
    const u16* vb = vbuf[cur];
    // ---- bias groups: 6 aligned 8B reads -> 24 f32
    float bvf[6][4];
    #pragma unroll
    for (int j = 0; j < 6; ++j) {
      const uint32_t u0 = rbp32[dwb + (k0 >> 1) + 8 * j];
      const uint32_t u1 = rbp32[dwb + (k0 >> 1) + 8 * j + 1];
      bvf[j][0] = bflo(u0); bvf[j][1] = bfhi(u0);
      bvf[j][2] = bflo(u1); bvf[j][3] = bfhi(u1);
    }
    // ---- S^T = K . Q^T for 3 subtiles (each K frag feeds 3 MFMA)
    f32x4 st[3][4] = {};
    __builtin_amdgcn_s_setprio(1);
    #pragma unroll
    for (int kc = 0; kc < 4; ++kc) {
      const int row = kc * 16 + lo16;
      const bf16x8 kf0 = ld_bf8(kb + row * 64 + ((g ^ rswz) << 3));
      const bf16x8 kf1 = ld_bf8(kb + row * 64 + (((4 + g) ^ rswz) << 3));
      #pragma unroll
      for (int s = 0; s < 3; ++s) {
        st[s][kc] = mfma16(kf0, qf[s][0], st[s][kc]);
        st[s][kc] = mfma16(kf1, qf[s][1], st[s][kc]);
      }
    }
    __builtin_amdgcn_s_setprio(0);
    // ---- p = 2^(s*c1 + bias'); lane-local l; pack to P slab
    #pragma unroll
    for (int s = 0; s < 3; ++s) {
      char* plb = (char*)plds[w][s];
      #pragma unroll
      for (int kc = 0; kc < 4; ++kc) {
        #pragma unroll
        for (int r = 0; r < 4; ++r) {
          float p = exp2_raw(__builtin_fmaf(st[s][kc][r], c1, bvf[kc - s + 2][r]));
          st[s][kc][r] = p;
          l_part[s] += p;
        }
        uint2 pr;
        pr.x = pkbf(st[s][kc][0], st[s][kc][1]);
        pr.y = pkbf(st[s][kc][2], st[s][kc][3]);
        *(uint2*)(plb + wbase + ((kc * 32 + g * 8) ^ pswz)) = pr;
      }
    }
    // ---- PV: each V frag feeds 3 MFMA
    __builtin_amdgcn_s_setprio(1);
    #pragma unroll
    for (int t = 0; t < 2; ++t) {
      bf16x8 pb[3];
      #pragma unroll
      for (int s = 0; s < 3; ++s)
        pb[s] = ld_bf8((const u16*)((char*)plds[w][s] + wbase + ((t * 64 + g * 16) ^ pswz)));
      #pragma unroll
      for (int fc = 0; fc < 4; ++fc) {
        const int row = fc * 16 + lo16;
        const bf16x8 vf = ld_bf8(vb + row * 64 + (((t * 4 + g) ^ rswz) << 3));
        #pragma unroll
        for (int s = 0; s < 3; ++s)
          acc[s][fc] = mfma16(vf, pb[s], acc[s][fc]);
      }
    }
    __builtin_amdgcn_s_setprio(0);
    __builtin_amdgcn_s_barrier();        // reads of buf[cur] done before overwrite
    cur = nxt;
  }
  // ---- epilogue per subtile
  const int b = bh >> 3;
  #pragma unroll
  for (int s = 0; s < 3; ++s) {
    float l_r = l_part[s];
    l_r += __shfl_xor(l_r, 16);
    l_r += __shfl_xor(l_r, 32);
    const float inv = 1.0f / l_r;
    u16* orow = O + ((size_t)(b * NSEQ + q0 + s * 16 + lo16)) * DMODEL + h * HD;
    #pragma unroll
    for (int fc = 0; fc < 4; ++fc) {
      uint2 o4;
      o4.x = pkbf(acc[s][fc][0] * inv, acc[s][fc][1] * inv);
      o4.y = pkbf(acc[s][fc][2] * inv, acc[s][fc][3] * inv);
      *(uint2*)(orow + fc * 16 + g * 4) = o4;
    }
  }
#undef STAGE
}

// ---------------------------------------------------------------- launch
extern "C" void kernel_launch(void* const* d_in, const int* in_sizes, int n_in,
                              void* d_out, int out_size, void* d_ws, size_t ws_size,
                              hipStream_t stream) {
  const float* vis   = (const float*)d_in[0];
  const float* txt   = (const float*)d_in[1];
  const float* WQ    = (const float*)d_in[2];
  const float* bQ    = (const float*)d_in[3];
  const float* WK    = (const float*)d_in[4];
  const float* bK    = (const float*)d_in[5];
  const float* WV    = (const float*)d_in[6];
  const float* bV    = (const float*)d_in[7];
  const float* WO    = (const float*)d_in[8];
  const float* bO    = (const float*)d_in[9];
  const float* table = (const float*)d_in[10];
  const float* gamma = (const float*)d_in[11];
  const float* beta  = (const float*)d_in[12];
  float* out = (float*)d_out;

  char* p = (char*)d_ws;
  u16* zn    = (u16*)p; p += (size_t)NM * DMODEL * 2;
  u16* wqkvt = (u16*)p; p += (size_t)3 * DMODEL * DMODEL * 2;
  u16* wot   = (u16*)p; p += (size_t)DMODEL * DMODEL * 2;
  u16* q     = (u16*)p; p += (size_t)NM * DMODEL * 2;
  u16* k     = (u16*)p; p += (size_t)NM * DMODEL * 2;
  u16* vt    = (u16*)p; p += (size_t)NM * DMODEL * 2;
  u16* o     = (u16*)p; p += (size_t)NM * DMODEL * 2;

  hipLaunchKernelGGL(ln_kernel, dim3(NM / 4), dim3(256), 0, stream,
                     vis, txt, gamma, beta, zn);
  hipLaunchKernelGGL(wtrans_kernel, dim3(16, 16, 4), dim3(256), 0, stream,
                     WQ, WK, WV, WO, wqkvt, wot);
  hipLaunchKernelGGL(gemm_qkv, dim3(16, 48), dim3(256), 0, stream,
                     zn, wqkvt, bQ, bK, bV, q, k, vt);
  hipLaunchKernelGGL(attn_kernel, dim3(256), dim3(256), 0, stream,
                     q, k, vt, table, o);
  hipLaunchKernelGGL(gemm_oproj, dim3(8, 96), dim3(256), 0, stream,
                     o, wot, bO, out);
}

// Round 11
// 82.445 us; speedup vs baseline: 1.1040x; 1.1040x over previous
//
#include <hip/hip_runtime.h>
#include <stdint.h>

#define NSEQ   1536
#define NBATCH 4
#define NM     (NBATCH * NSEQ)   // 6144
#define DMODEL 512
#define NHEAD  8
#define HD     64
#define TBLN   2047              // 2*1024-1

typedef __attribute__((ext_vector_type(4))) float  f32x4;
typedef __attribute__((ext_vector_type(4))) int    i32x4;
typedef __attribute__((ext_vector_type(8))) __bf16 bf16x8;
typedef unsigned short u16;

static_assert(sizeof(bf16x8) == 16, "bf16x8 must be 16B");

__device__ inline u16 f2bf(float f) {
  union { float f; uint32_t u; } v; v.f = f;
  uint32_t u = v.u;
  return (u16)((u + 0x7fffu + ((u >> 16) & 1u)) >> 16);   // RNE
}

__device__ inline bf16x8 ld_bf8(const u16* p) {
  i32x4 v = *(const i32x4*)p;
  return __builtin_bit_cast(bf16x8, v);
}

__device__ inline f32x4 mfma16(bf16x8 a, bf16x8 b, f32x4 c) {
  return __builtin_amdgcn_mfma_f32_16x16x32_bf16(a, b, c, 0, 0, 0);
}

__device__ inline void gload_lds16(const void* g, void* l) {
  __builtin_amdgcn_global_load_lds(
      (__attribute__((address_space(1))) void*)(g),
      (__attribute__((address_space(3))) void*)(l), 16, 0, 0);
}

__device__ inline uint32_t pkbf(float a, float b) {
  uint32_t r;
  asm("v_cvt_pk_bf16_f32 %0, %1, %2" : "=v"(r) : "v"(a), "v"(b));
  return r;   // lo16 = bf16(a), hi16 = bf16(b)
}

__device__ inline float exp2_raw(float x) {   // |x| small: no libm guards
  float r;
  asm("v_exp_f32 %0, %1" : "=v"(r) : "v"(x));
  return r;
}

__device__ inline float bfhi(uint32_t u) {    // high bf16 -> f32
  union { uint32_t u; float f; } v; v.u = u & 0xffff0000u; return v.f;
}
__device__ inline float bflo(uint32_t u) {    // low bf16 -> f32
  union { uint32_t u; float f; } v; v.u = u << 16; return v.f;
}

// ---------------------------------------------------------------- LayerNorm
__global__ __launch_bounds__(256) void ln_kernel(
    const float* __restrict__ vis, const float* __restrict__ txt,
    const float* __restrict__ gamma, const float* __restrict__ beta,
    u16* __restrict__ zn) {
  const int lane = threadIdx.x & 63;
  const int row  = blockIdx.x * 4 + (threadIdx.x >> 6);
  const int b = row / NSEQ, n = row - b * NSEQ;
  const float* src = (n < 1024) ? (vis + ((size_t)b * 1024 + n) * DMODEL)
                                : (txt + ((size_t)b * 512 + (n - 1024)) * DMODEL);
  const float4* s4 = (const float4*)src;
  float4 x0 = s4[lane], x1 = s4[lane + 64];
  float s = x0.x + x0.y + x0.z + x0.w + x1.x + x1.y + x1.z + x1.w;
  float q = x0.x*x0.x + x0.y*x0.y + x0.z*x0.z + x0.w*x0.w
          + x1.x*x1.x + x1.y*x1.y + x1.z*x1.z + x1.w*x1.w;
  #pragma unroll
  for (int m = 1; m < 64; m <<= 1) { s += __shfl_xor(s, m); q += __shfl_xor(q, m); }
  const float mean = s * (1.0f / 512.0f);
  const float var  = q * (1.0f / 512.0f) - mean * mean;
  const float rstd = rsqrtf(var + 1e-5f);
  const float4* g4 = (const float4*)gamma;
  const float4* b4 = (const float4*)beta;
  float4 g0 = g4[lane], g1 = g4[lane + 64], p0 = b4[lane], p1 = b4[lane + 64];
  u16* dst = zn + (size_t)row * DMODEL;
  ushort4 o0, o1;
  o0.x = f2bf((x0.x - mean) * rstd * g0.x + p0.x);
  o0.y = f2bf((x0.y - mean) * rstd * g0.y + p0.y);
  o0.z = f2bf((x0.z - mean) * rstd * g0.z + p0.z);
  o0.w = f2bf((x0.w - mean) * rstd * g0.w + p0.w);
  o1.x = f2bf((x1.x - mean) * rstd * g1.x + p1.x);
  o1.y = f2bf((x1.y - mean) * rstd * g1.y + p1.y);
  o1.z = f2bf((x1.z - mean) * rstd * g1.z + p1.z);
  o1.w = f2bf((x1.w - mean) * rstd * g1.w + p1.w);
  *(ushort4*)(dst + lane * 4)        = o0;
  *(ushort4*)(dst + (lane + 64) * 4) = o1;
}

// ------------------------------------------------- weight transpose -> bf16
__global__ __launch_bounds__(256) void wtrans_kernel(
    const float* __restrict__ WQ, const float* __restrict__ WK,
    const float* __restrict__ WV, const float* __restrict__ WO,
    u16* __restrict__ wqkvt, u16* __restrict__ wot) {
  __shared__ float t[32][33];
  const int m = blockIdx.z;
  const float* W = (m == 0) ? WQ : (m == 1) ? WK : (m == 2) ? WV : WO;
  const int n0 = blockIdx.x * 32, k0 = blockIdx.y * 32;
  const int tx = threadIdx.x & 31, ty = threadIdx.x >> 5;
  #pragma unroll
  for (int j = 0; j < 4; ++j)
    t[ty + j * 8][tx] = W[(size_t)(k0 + ty + j * 8) * DMODEL + n0 + tx];
  __syncthreads();
  u16* out = (m < 3) ? (wqkvt + (size_t)m * DMODEL * DMODEL) : wot;
  #pragma unroll
  for (int j = 0; j < 4; ++j)
    out[(size_t)(n0 + ty + j * 8) * DMODEL + k0 + tx] = f2bf(t[tx][ty + j * 8]);
}

// ------------------------------------------------------------- QKV GEMM
// 128(M) x 96(N) tile, BK=64, 4 waves (2x2), wave tile 64x48.
// grid 16x48 = 768 blocks = exactly 3 per CU (balanced).
__global__ __launch_bounds__(256) void gemm_qkv(
    const u16* __restrict__ A, const u16* __restrict__ Bt,
    const float* __restrict__ bQ, const float* __restrict__ bK, const float* __restrict__ bV,
    u16* __restrict__ Q, u16* __restrict__ Kk, u16* __restrict__ Vt) {
  __shared__ __align__(16) u16 lat[128 * 64];
  __shared__ __align__(16) u16 lbt[96 * 64];
  const int tid = threadIdx.x, lane = tid & 63, w = tid >> 6;
  const int wr = w >> 1, wc = w & 1;
  const int m0 = blockIdx.y * 128, n0 = blockIdx.x * 96;
  f32x4 acc[4][3] = {};
  for (int kt = 0; kt < 8; ++kt) {
    const int k0 = kt * 64;
    #pragma unroll
    for (int i = 0; i < 4; ++i) {
      int ch = tid + 256 * i;                 // A: 1024 chunks
      int row = ch >> 3, pc = ch & 7;
      int kk = k0 + ((pc ^ (row & 7)) << 3);
      gload_lds16(A + (size_t)(m0 + row) * DMODEL + kk, lat + (size_t)ch * 8);
    }
    #pragma unroll
    for (int i = 0; i < 3; ++i) {
      int ch = tid + 256 * i;                 // B: 768 chunks
      int row = ch >> 3, pc = ch & 7;
      int kk = k0 + ((pc ^ (row & 7)) << 3);
      gload_lds16(Bt + (size_t)(n0 + row) * DMODEL + kk, lbt + (size_t)ch * 8);
    }
    __syncthreads();
    #pragma unroll
    for (int ks = 0; ks < 2; ++ks) {
      bf16x8 af[4], bfr[3];
      const int cc = ks * 4 + (lane >> 4);
      #pragma unroll
      for (int f = 0; f < 4; ++f) {
        int ra = wr * 64 + f * 16 + (lane & 15);
        af[f]  = ld_bf8(lat + ra * 64 + ((cc ^ (ra & 7)) << 3));
      }
      #pragma unroll
      for (int f = 0; f < 3; ++f) {
        int rb = wc * 48 + f * 16 + (lane & 15);
        bfr[f] = ld_bf8(lbt + rb * 64 + ((cc ^ (rb & 7)) << 3));
      }
      #pragma unroll
      for (int fr = 0; fr < 4; ++fr)
        #pragma unroll
        for (int fc = 0; fc < 3; ++fc)
          acc[fr][fc] = mfma16(af[fr], bfr[fc], acc[fr][fc]);
    }
    __syncthreads();
  }
  #pragma unroll
  for (int fr = 0; fr < 4; ++fr) {
    const int mbase = m0 + wr * 64 + fr * 16 + ((lane >> 4) << 2);
    const int b = mbase / NSEQ;
    const int nseq = mbase - b * NSEQ;
    #pragma unroll
    for (int fc = 0; fc < 3; ++fc) {
      const int col = n0 + wc * 48 + fc * 16 + (lane & 15);
      const int which = col >> 9;
      const int cw = col & 511;
      const int h = cw >> 6, d = cw & 63;
      const float bias = (which == 0) ? bQ[cw] : (which == 1) ? bK[cw] : bV[cw];
      if (which < 2) {
        u16* dst = ((which == 0) ? Q : Kk) + ((size_t)(b * NHEAD + h) * NSEQ + nseq) * HD + d;
        #pragma unroll
        for (int r = 0; r < 4; ++r) dst[(size_t)r * HD] = f2bf(acc[fr][fc][r] + bias);
      } else {
        ushort4 pv;
        pv.x = f2bf(acc[fr][fc][0] + bias);
        pv.y = f2bf(acc[fr][fc][1] + bias);
        pv.z = f2bf(acc[fr][fc][2] + bias);
        pv.w = f2bf(acc[fr][fc][3] + bias);
        *(ushort4*)(Vt + ((size_t)(b * NHEAD + h) * HD + d) * NSEQ + nseq) = pv;
      }
    }
  }
}

// ------------------------------------------------------------ O-proj GEMM
// 64x64 tile, 4 waves (2x2), wave tile 32x32. grid 8x96 = 768 blocks (3/CU).
__global__ __launch_bounds__(256) void gemm_oproj(
    const u16* __restrict__ A, const u16* __restrict__ Bt,
    const float* __restrict__ bO, float* __restrict__ out) {
  __shared__ __align__(16) u16 lat[64 * 64];
  __shared__ __align__(16) u16 lbt[64 * 64];
  const int tid = threadIdx.x, lane = tid & 63, w = tid >> 6;
  const int wr = w >> 1, wc = w & 1;
  const int m0 = blockIdx.y * 64, n0 = blockIdx.x * 64;
  f32x4 acc[2][2] = {};
  for (int kt = 0; kt < 8; ++kt) {
    const int k0 = kt * 64;
    #pragma unroll
    for (int i = 0; i < 2; ++i) {
      int ch = tid + 256 * i;                 // 512 chunks each
      int row = ch >> 3, pc = ch & 7;
      int kk = k0 + ((pc ^ (row & 7)) << 3);
      gload_lds16(A  + (size_t)(m0 + row) * DMODEL + kk, lat + (size_t)ch * 8);
      gload_lds16(Bt + (size_t)(n0 + row) * DMODEL + kk, lbt + (size_t)ch * 8);
    }
    __syncthreads();
    #pragma unroll
    for (int ks = 0; ks < 2; ++ks) {
      bf16x8 af[2], bfr[2];
      const int cc = ks * 4 + (lane >> 4);
      #pragma unroll
      for (int f = 0; f < 2; ++f) {
        int ra = wr * 32 + f * 16 + (lane & 15);
        af[f]  = ld_bf8(lat + ra * 64 + ((cc ^ (ra & 7)) << 3));
        int rb = wc * 32 + f * 16 + (lane & 15);
        bfr[f] = ld_bf8(lbt + rb * 64 + ((cc ^ (rb & 7)) << 3));
      }
      #pragma unroll
      for (int fr = 0; fr < 2; ++fr)
        #pragma unroll
        for (int fc = 0; fc < 2; ++fc)
          acc[fr][fc] = mfma16(af[fr], bfr[fc], acc[fr][fc]);
    }
    __syncthreads();
  }
  #pragma unroll
  for (int fr = 0; fr < 2; ++fr) {
    const int mbase = m0 + wr * 32 + fr * 16 + ((lane >> 4) << 2);
    #pragma unroll
    for (int fc = 0; fc < 2; ++fc) {
      const int col = n0 + wc * 32 + fc * 16 + (lane & 15);
      const float bias = bO[col];
      float* dst = out + (size_t)mbase * DMODEL + col;
      #pragma unroll
      for (int r = 0; r < 4; ++r) dst[(size_t)r * DMODEL] = acc[fr][fc][r] + bias;
    }
  }
}

// ------------------------------------------------------------ attention v11
// In-block KV-split: 8 waves (512 thr); waves 0-3 process q-tile for
// k in [0,768), waves 4-7 same q for k in [768,1536). No-max softmax makes
// partials linearly additive -> combine = f32 adds through LDS at the end.
// Each half double-buffers its own 64x64 K/V tiles; v9/v10-validated sync
// (counted vmcnt(4) + two arrival barriers). 48q/wave amortization kept.
// 124 KB LDS, 256 blocks = 1 block/CU, 8 waves/CU = 2/SIMD.
__global__ __launch_bounds__(512, 1) void attn_kernel(
    const u16* __restrict__ Q, const u16* __restrict__ K,
    const u16* __restrict__ Vt, const float* __restrict__ table,
    u16* __restrict__ O) {
  // manual LDS carve (single array guarantees layout):
  //  [0, 12288)        bf16 bias rb2[2][3072]
  //  [12288, 45056)    kbuf: half hf, dbuf b -> +(hf*2+b)*8192 B   (dead after loop -> combine scratch)
  //  [45056, 77824)    vbuf: same indexing
  //  [77824, 126976)   plds: wave w -> +w*6144 B (3 subtiles x 2 KB)
  __shared__ __align__(16) char smem[126976];
  u16* rb2k = (u16*)smem;
  const int tid = threadIdx.x, lane = tid & 63, w = tid >> 6;
  const int bid = blockIdx.x;
  const int xcd = bid & 7, idx = bid >> 3;        // idx in [0,32)
  const int bh  = xcd * 4 + (idx & 3);
  const int qt  = idx >> 2;                       // [0,8)
  const int h   = bh & (NHEAD - 1);
  // rev[t] = bf16(table[clamp(2558-t,0,2046)][h] * log2e); rb2[c][x] = rev[x+c]
  for (int t = tid; t < 2 * 3072; t += 512) {
    const int c = (t >= 3072) ? 1 : 0;
    const int x = t - c * 3072;
    int src = 2558 - (x + c);
    src = src < 0 ? 0 : (src > 2046 ? 2046 : src);
    rb2k[c * 3072 + x] = f2bf(table[(size_t)src * NHEAD + h] * 1.4426950408889634f);
  }

  const int lo16 = lane & 15, g = lane >> 4;
  const int ws = w & 3;                  // q-tile index within block
  const int hf = w >> 2;                 // k-half (0 or 1)
  const int kbase = hf * 768;
  const int q0 = qt * 192 + ws * 48;
  const u16* Qb = Q  + (size_t)bh * NSEQ * HD;
  const u16* Kb = K  + (size_t)bh * NSEQ * HD;
  const u16* Vb = Vt + (size_t)bh * HD * NSEQ;

  // staging: thread's half shf = tid>>8, tloc = tid&255; 4 loads/thread per kt.
  const int tloc = tid & 255, shf = tid >> 8;
  const int skbase = shf * 768;
  u16* kl0 = (u16*)(smem + 12288) + shf * 2 * 4096;
  u16* vl0 = (u16*)(smem + 45056) + shf * 2 * 4096;
#define STAGE(b, k0loc)                                                       \
  do {                                                                        \
    _Pragma("unroll")                                                         \
    for (int i = 0; i < 2; ++i) {                                             \
      int ch = tloc + 256 * i;                                                \
      int row = ch >> 3, pc = ch & 7;                                         \
      int col = (pc ^ (row & 7)) << 3;                                        \
      gload_lds16(Kb + (size_t)(skbase + (k0loc) + row) * HD + col,           \
                  kl0 + (size_t)(b) * 4096 + ch * 8);                         \
      gload_lds16(Vb + (size_t)row * NSEQ + skbase + (k0loc) + col,           \
                  vl0 + (size_t)(b) * 4096 + ch * 8);                         \
    }                                                                         \
  } while (0)

  bf16x8 qf[3][2];
  #pragma unroll
  for (int s = 0; s < 3; ++s)
    #pragma unroll
    for (int kd = 0; kd < 2; ++kd)
      qf[s][kd] = ld_bf8(Qb + (size_t)(q0 + s * 16 + lo16) * HD + kd * 32 + g * 8);

  float l_part[3] = {0.f, 0.f, 0.f};
  f32x4 acc[3][4] = {};

  char* plb = smem + 77824 + w * 6144;   // wave-private P (3 x 2 KB)
  const int pswz  = (lo16 & 7) << 4;
  const int wbase = lo16 * 128;
  const int rswz  = lo16 & 7;
  // bias: value(s,kc,r) = rev[B + kglob + 16*(kc - s + 2) + r]
  const int B   = 1535 - q0 - lo16 + 4 * g - 32;
  const int c2  = B & 1;
  const int dwb = (B - c2) >> 1;
  const uint32_t* rbp32 = (const uint32_t*)(rb2k + c2 * 3072);
  const float c1 = 0.125f * 1.4426950408889634f;  // scale * log2(e)

  STAGE(0, 0);
  __syncthreads();                       // bias writes + stage0 drain
  int cur = 0;

  for (int kt = 0; kt < 12; ++kt) {
    const int kglob = kbase + kt * 64;
    const int nxt = cur ^ 1;
    if (kt < 11) {
      STAGE(nxt, (kt + 1) * 64);
      asm volatile("s_waitcnt vmcnt(4)" ::: "memory");
    } else {
      asm volatile("s_waitcnt vmcnt(0)" ::: "memory");
    }
    __builtin_amdgcn_s_barrier();        // stage(kt) visible; stage(kt+1) in flight
    const u16* kb = (u16*)(smem + 12288) + (hf * 2 + cur) * 4096;
    const u16* vb = (u16*)(smem + 45056) + (hf * 2 + cur) * 4096;
    // ---- bias groups: 6 aligned 8B reads -> 24 f32
    float bvf[6][4];
    #pragma unroll
    for (int j = 0; j < 6; ++j) {
      const uint32_t u0 = rbp32[dwb + (kglob >> 1) + 8 * j];
      const uint32_t u1 = rbp32[dwb + (kglob >> 1) + 8 * j + 1];
      bvf[j][0] = bflo(u0); bvf[j][1] = bfhi(u0);
      bvf[j][2] = bflo(u1); bvf[j][3] = bfhi(u1);
    }
    // ---- S^T = K . Q^T for 3 subtiles (each K frag feeds 3 MFMA)
    f32x4 st[3][4] = {};
    __builtin_amdgcn_s_setprio(1);
    #pragma unroll
    for (int kc = 0; kc < 4; ++kc) {
      const int row = kc * 16 + lo16;
      const bf16x8 kf0 = ld_bf8(kb + row * 64 + ((g ^ rswz) << 3));
      const bf16x8 kf1 = ld_bf8(kb + row * 64 + (((4 + g) ^ rswz) << 3));
      #pragma unroll
      for (int s = 0; s < 3; ++s) {
        st[s][kc] = mfma16(kf0, qf[s][0], st[s][kc]);
        st[s][kc] = mfma16(kf1, qf[s][1], st[s][kc]);
      }
    }
    __builtin_amdgcn_s_setprio(0);
    // ---- p = 2^(s*c1 + bias'); lane-local l; pack to P slab
    #pragma unroll
    for (int s = 0; s < 3; ++s) {
      char* pls = plb + s * 2048;
      #pragma unroll
      for (int kc = 0; kc < 4; ++kc) {
        #pragma unroll
        for (int r = 0; r < 4; ++r) {
          float p = exp2_raw(__builtin_fmaf(st[s][kc][r], c1, bvf[kc - s + 2][r]));
          st[s][kc][r] = p;
          l_part[s] += p;
        }
        uint2 pr;
        pr.x = pkbf(st[s][kc][0], st[s][kc][1]);
        pr.y = pkbf(st[s][kc][2], st[s][kc][3]);
        *(uint2*)(pls + wbase + ((kc * 32 + g * 8) ^ pswz)) = pr;
      }
    }
    // ---- PV: each V frag feeds 3 MFMA
    __builtin_amdgcn_s_setprio(1);
    #pragma unroll
    for (int t = 0; t < 2; ++t) {
      bf16x8 pb[3];
      #pragma unroll
      for (int s = 0; s < 3; ++s)
        pb[s] = ld_bf8((const u16*)(plb + s * 2048 + wbase + ((t * 64 + g * 16) ^ pswz)));
      #pragma unroll
      for (int fc = 0; fc < 4; ++fc) {
        const int row = fc * 16 + lo16;
        const bf16x8 vf = ld_bf8(vb + row * 64 + (((t * 4 + g) ^ rswz) << 3));
        #pragma unroll
        for (int s = 0; s < 3; ++s)
          acc[s][fc] = mfma16(vf, pb[s], acc[s][fc]);
      }
    }
    __builtin_amdgcn_s_setprio(0);
    __builtin_amdgcn_s_barrier();        // reads of buf[cur] done before overwrite
    cur = nxt;
  }
  // ---- combine halves: h1 dumps partials into dead kbuf/vbuf region
  float* scr = (float*)(smem + 12288);   // 64 KB free; need 4 x 13056 B
  if (hf == 1) {
    float* wb = scr + ws * 3264;
    #pragma unroll
    for (int s = 0; s < 3; ++s) {
      #pragma unroll
      for (int fc = 0; fc < 4; ++fc)
        ((f32x4*)wb)[(s * 4 + fc) * 64 + lane] = acc[s][fc];
      wb[3072 + s * 64 + lane] = l_part[s];
    }
  }
  __syncthreads();
  if (hf == 0) {
    const float* rb = scr + ws * 3264;
    #pragma unroll
    for (int s = 0; s < 3; ++s) {
      #pragma unroll
      for (int fc = 0; fc < 4; ++fc)
        acc[s][fc] += ((const f32x4*)rb)[(s * 4 + fc) * 64 + lane];
      l_part[s] += rb[3072 + s * 64 + lane];
    }
    const int b = bh >> 3;
    #pragma unroll
    for (int s = 0; s < 3; ++s) {
      float l_r = l_part[s];
      l_r += __shfl_xor(l_r, 16);
      l_r += __shfl_xor(l_r, 32);
      const float inv = 1.0f / l_r;
      u16* orow = O + ((size_t)(b * NSEQ + q0 + s * 16 + lo16)) * DMODEL + h * HD;
      #pragma unroll
      for (int fc = 0; fc < 4; ++fc) {
        uint2 o4;
        o4.x = pkbf(acc[s][fc][0] * inv, acc[s][fc][1] * inv);
        o4.y = pkbf(acc[s][fc][2] * inv, acc[s][fc][3] * inv);
        *(uint2*)(orow + fc * 16 + g * 4) = o4;
      }
    }
  }
#undef STAGE
}

// ---------------------------------------------------------------- launch
extern "C" void kernel_launch(void* const* d_in, const int* in_sizes, int n_in,
                              void* d_out, int out_size, void* d_ws, size_t ws_size,
                              hipStream_t stream) {
  const float* vis   = (const float*)d_in[0];
  const float* txt   = (const float*)d_in[1];
  const float* WQ    = (const float*)d_in[2];
  const float* bQ    = (const float*)d_in[3];
  const float* WK    = (const float*)d_in[4];
  const float* bK    = (const float*)d_in[5];
  const float* WV    = (const float*)d_in[6];
  const float* bV    = (const float*)d_in[7];
  const float* WO    = (const float*)d_in[8];
  const float* bO    = (const float*)d_in[9];
  const float* table = (const float*)d_in[10];
  const float* gamma = (const float*)d_in[11];
  const float* beta  = (const float*)d_in[12];
  float* out = (float*)d_out;

  char* p = (char*)d_ws;
  u16* zn    = (u16*)p; p += (size_t)NM * DMODEL * 2;
  u16* wqkvt = (u16*)p; p += (size_t)3 * DMODEL * DMODEL * 2;
  u16* wot   = (u16*)p; p += (size_t)DMODEL * DMODEL * 2;
  u16* q     = (u16*)p; p += (size_t)NM * DMODEL * 2;
  u16* k     = (u16*)p; p += (size_t)NM * DMODEL * 2;
  u16* vt    = (u16*)p; p += (size_t)NM * DMODEL * 2;
  u16* o     = (u16*)p; p += (size_t)NM * DMODEL * 2;

  hipLaunchKernelGGL(ln_kernel, dim3(NM / 4), dim3(256), 0, stream,
                     vis, txt, gamma, beta, zn);
  hipLaunchKernelGGL(wtrans_kernel, dim3(16, 16, 4), dim3(256), 0, stream,
                     WQ, WK, WV, WO, wqkvt, wot);
  hipLaunchKernelGGL(gemm_qkv, dim3(16, 48), dim3(256), 0, stream,
                     zn, wqkvt, bQ, bK, bV, q, k, vt);
  hipLaunchKernelGGL(attn_kernel, dim3(256), dim3(512), 0, stream,
                     q, k, vt, table, o);
  hipLaunchKernelGGL(gemm_oproj, dim3(8, 96), dim3(256), 0, stream,
                     o, wot, bO, out);
}

// Round 14
// 81.992 us; speedup vs baseline: 1.1102x; 1.0055x over previous
//
#include <hip/hip_runtime.h>
#include <stdint.h>

#define NSEQ   1536
#define NBATCH 4
#define NM     (NBATCH * NSEQ)   // 6144
#define DMODEL 512
#define NHEAD  8
#define HD     64
#define TBLN   2047              // 2*1024-1

typedef __attribute__((ext_vector_type(4)))  float f32x4;
typedef __attribute__((ext_vector_type(16))) float f32x16;
typedef __attribute__((ext_vector_type(4)))  int   i32x4;
typedef __attribute__((ext_vector_type(2)))  unsigned u32x2;
typedef __attribute__((ext_vector_type(8)))  __bf16 bf16x8;
typedef unsigned short u16;

static_assert(sizeof(bf16x8) == 16, "bf16x8 must be 16B");

__device__ inline u16 f2bf(float f) {
  union { float f; uint32_t u; } v; v.f = f;
  uint32_t u = v.u;
  return (u16)((u + 0x7fffu + ((u >> 16) & 1u)) >> 16);   // RNE
}

__device__ inline bf16x8 ld_bf8(const u16* p) {
  i32x4 v = *(const i32x4*)p;
  return __builtin_bit_cast(bf16x8, v);
}

__device__ inline f32x4 mfma16(bf16x8 a, bf16x8 b, f32x4 c) {
  return __builtin_amdgcn_mfma_f32_16x16x32_bf16(a, b, c, 0, 0, 0);
}

__device__ inline f32x16 mfma32(bf16x8 a, bf16x8 b, f32x16 c) {
  return __builtin_amdgcn_mfma_f32_32x32x16_bf16(a, b, c, 0, 0, 0);
}

__device__ inline void gload_lds16(const void* g, void* l) {
  __builtin_amdgcn_global_load_lds(
      (__attribute__((address_space(1))) void*)(g),
      (__attribute__((address_space(3))) void*)(l), 16, 0, 0);
}

__device__ inline uint32_t pkbf(float a, float b) {
  uint32_t r;
  asm("v_cvt_pk_bf16_f32 %0, %1, %2" : "=v"(r) : "v"(a), "v"(b));
  return r;   // lo16 = bf16(a), hi16 = bf16(b)
}

// Exchange halves across the lane<32 / lane>=32 split between two words.
__device__ inline void plswap(uint32_t& a, uint32_t& b, int hi) {
#if __has_builtin(__builtin_amdgcn_permlane32_swap)
  u32x2 r = __builtin_amdgcn_permlane32_swap(a, b, false, false);
  a = r[0]; b = r[1];
#else
  const uint32_t as = (uint32_t)__shfl_xor((int)a, 32);
  const uint32_t bs = (uint32_t)__shfl_xor((int)b, 32);
  const uint32_t na = hi ? bs : a;   // [a_lo | b_lo]
  const uint32_t nb = hi ? b : as;   // [a_hi | b_hi]
  a = na; b = nb;
#endif
}

__device__ inline float exp2_raw(float x) {   // |x| small: no libm guards
  float r;
  asm("v_exp_f32 %0, %1" : "=v"(r) : "v"(x));
  return r;
}

__device__ inline float bfhi(uint32_t u) {
  union { uint32_t u; float f; } v; v.u = u & 0xffff0000u; return v.f;
}
__device__ inline float bflo(uint32_t u) {
  union { uint32_t u; float f; } v; v.u = u << 16; return v.f;
}

// ---------------------------------------------------------------- LayerNorm
__global__ __launch_bounds__(256) void ln_kernel(
    const float* __restrict__ vis, const float* __restrict__ txt,
    const float* __restrict__ gamma, const float* __restrict__ beta,
    u16* __restrict__ zn) {
  const int lane = threadIdx.x & 63;
  const int row  = blockIdx.x * 4 + (threadIdx.x >> 6);
  const int b = row / NSEQ, n = row - b * NSEQ;
  const float* src = (n < 1024) ? (vis + ((size_t)b * 1024 + n) * DMODEL)
                                : (txt + ((size_t)b * 512 + (n - 1024)) * DMODEL);
  const float4* s4 = (const float4*)src;
  float4 x0 = s4[lane], x1 = s4[lane + 64];
  float s = x0.x + x0.y + x0.z + x0.w + x1.x + x1.y + x1.z + x1.w;
  float q = x0.x*x0.x + x0.y*x0.y + x0.z*x0.z + x0.w*x0.w
          + x1.x*x1.x + x1.y*x1.y + x1.z*x1.z + x1.w*x1.w;
  #pragma unroll
  for (int m = 1; m < 64; m <<= 1) { s += __shfl_xor(s, m); q += __shfl_xor(q, m); }
  const float mean = s * (1.0f / 512.0f);
  const float var  = q * (1.0f / 512.0f) - mean * mean;
  const float rstd = rsqrtf(var + 1e-5f);
  const float4* g4 = (const float4*)gamma;
  const float4* b4 = (const float4*)beta;
  float4 g0 = g4[lane], g1 = g4[lane + 64], p0 = b4[lane], p1 = b4[lane + 64];
  u16* dst = zn + (size_t)row * DMODEL;
  ushort4 o0, o1;
  o0.x = f2bf((x0.x - mean) * rstd * g0.x + p0.x);
  o0.y = f2bf((x0.y - mean) * rstd * g0.y + p0.y);
  o0.z = f2bf((x0.z - mean) * rstd * g0.z + p0.z);
  o0.w = f2bf((x0.w - mean) * rstd * g0.w + p0.w);
  o1.x = f2bf((x1.x - mean) * rstd * g1.x + p1.x);
  o1.y = f2bf((x1.y - mean) * rstd * g1.y + p1.y);
  o1.z = f2bf((x1.z - mean) * rstd * g1.z + p1.z);
  o1.w = f2bf((x1.w - mean) * rstd * g1.w + p1.w);
  *(ushort4*)(dst + lane * 4)        = o0;
  *(ushort4*)(dst + (lane + 64) * 4) = o1;
}

// ------------------------------------------------- weight transpose -> bf16
__global__ __launch_bounds__(256) void wtrans_kernel(
    const float* __restrict__ WQ, const float* __restrict__ WK,
    const float* __restrict__ WV, const float* __restrict__ WO,
    u16* __restrict__ wqkvt, u16* __restrict__ wot) {
  __shared__ float t[32][33];
  const int m = blockIdx.z;
  const float* W = (m == 0) ? WQ : (m == 1) ? WK : (m == 2) ? WV : WO;
  const int n0 = blockIdx.x * 32, k0 = blockIdx.y * 32;
  const int tx = threadIdx.x & 31, ty = threadIdx.x >> 5;
  #pragma unroll
  for (int j = 0; j < 4; ++j)
    t[ty + j * 8][tx] = W[(size_t)(k0 + ty + j * 8) * DMODEL + n0 + tx];
  __syncthreads();
  u16* out = (m < 3) ? (wqkvt + (size_t)m * DMODEL * DMODEL) : wot;
  #pragma unroll
  for (int j = 0; j < 4; ++j)
    out[(size_t)(n0 + ty + j * 8) * DMODEL + k0 + tx] = f2bf(t[tx][ty + j * 8]);
}

// ------------------------------------------------------------- QKV GEMM
__global__ __launch_bounds__(256) void gemm_qkv(
    const u16* __restrict__ A, const u16* __restrict__ Bt,
    const float* __restrict__ bQ, const float* __restrict__ bK, const float* __restrict__ bV,
    u16* __restrict__ Q, u16* __restrict__ Kk, u16* __restrict__ Vt) {
  __shared__ __align__(16) u16 lat[128 * 64];
  __shared__ __align__(16) u16 lbt[96 * 64];
  const int tid = threadIdx.x, lane = tid & 63, w = tid >> 6;
  const int wr = w >> 1, wc = w & 1;
  const int m0 = blockIdx.y * 128, n0 = blockIdx.x * 96;
  f32x4 acc[4][3] = {};
  for (int kt = 0; kt < 8; ++kt) {
    const int k0 = kt * 64;
    #pragma unroll
    for (int i = 0; i < 4; ++i) {
      int ch = tid + 256 * i;
      int row = ch >> 3, pc = ch & 7;
      int kk = k0 + ((pc ^ (row & 7)) << 3);
      gload_lds16(A + (size_t)(m0 + row) * DMODEL + kk, lat + (size_t)ch * 8);
    }
    #pragma unroll
    for (int i = 0; i < 3; ++i) {
      int ch = tid + 256 * i;
      int row = ch >> 3, pc = ch & 7;
      int kk = k0 + ((pc ^ (row & 7)) << 3);
      gload_lds16(Bt + (size_t)(n0 + row) * DMODEL + kk, lbt + (size_t)ch * 8);
    }
    __syncthreads();
    #pragma unroll
    for (int ks = 0; ks < 2; ++ks) {
      bf16x8 af[4], bfr[3];
      const int cc = ks * 4 + (lane >> 4);
      #pragma unroll
      for (int f = 0; f < 4; ++f) {
        int ra = wr * 64 + f * 16 + (lane & 15);
        af[f]  = ld_bf8(lat + ra * 64 + ((cc ^ (ra & 7)) << 3));
      }
      #pragma unroll
      for (int f = 0; f < 3; ++f) {
        int rb = wc * 48 + f * 16 + (lane & 15);
        bfr[f] = ld_bf8(lbt + rb * 64 + ((cc ^ (rb & 7)) << 3));
      }
      #pragma unroll
      for (int fr = 0; fr < 4; ++fr)
        #pragma unroll
        for (int fc = 0; fc < 3; ++fc)
          acc[fr][fc] = mfma16(af[fr], bfr[fc], acc[fr][fc]);
    }
    __syncthreads();
  }
  #pragma unroll
  for (int fr = 0; fr < 4; ++fr) {
    const int mbase = m0 + wr * 64 + fr * 16 + ((lane >> 4) << 2);
    const int b = mbase / NSEQ;
    const int nseq = mbase - b * NSEQ;
    #pragma unroll
    for (int fc = 0; fc < 3; ++fc) {
      const int col = n0 + wc * 48 + fc * 16 + (lane & 15);
      const int which = col >> 9;
      const int cw = col & 511;
      const int h = cw >> 6, d = cw & 63;
      const float bias = (which == 0) ? bQ[cw] : (which == 1) ? bK[cw] : bV[cw];
      if (which < 2) {
        u16* dst = ((which == 0) ? Q : Kk) + ((size_t)(b * NHEAD + h) * NSEQ + nseq) * HD + d;
        #pragma unroll
        for (int r = 0; r < 4; ++r) dst[(size_t)r * HD] = f2bf(acc[fr][fc][r] + bias);
      } else {
        ushort4 pv;
        pv.x = f2bf(acc[fr][fc][0] + bias);
        pv.y = f2bf(acc[fr][fc][1] + bias);
        pv.z = f2bf(acc[fr][fc][2] + bias);
        pv.w = f2bf(acc[fr][fc][3] + bias);
        *(ushort4*)(Vt + ((size_t)(b * NHEAD + h) * HD + d) * NSEQ + nseq) = pv;
      }
    }
  }
}

// ------------------------------------------------------------ O-proj GEMM
__global__ __launch_bounds__(256) void gemm_oproj(
    const u16* __restrict__ A, const u16* __restrict__ Bt,
    const float* __restrict__ bO, float* __restrict__ out) {
  __shared__ __align__(16) u16 lat[64 * 64];
  __shared__ __align__(16) u16 lbt[64 * 64];
  const int tid = threadIdx.x, lane = tid & 63, w = tid >> 6;
  const int wr = w >> 1, wc = w & 1;
  const int m0 = blockIdx.y * 64, n0 = blockIdx.x * 64;
  f32x4 acc[2][2] = {};
  for (int kt = 0; kt < 8; ++kt) {
    const int k0 = kt * 64;
    #pragma unroll
    for (int i = 0; i < 2; ++i) {
      int ch = tid + 256 * i;
      int row = ch >> 3, pc = ch & 7;
      int kk = k0 + ((pc ^ (row & 7)) << 3);
      gload_lds16(A  + (size_t)(m0 + row) * DMODEL + kk, lat + (size_t)ch * 8);
      gload_lds16(Bt + (size_t)(n0 + row) * DMODEL + kk, lbt + (size_t)ch * 8);
    }
    __syncthreads();
    #pragma unroll
    for (int ks = 0; ks < 2; ++ks) {
      bf16x8 af[2], bfr[2];
      const int cc = ks * 4 + (lane >> 4);
      #pragma unroll
      for (int f = 0; f < 2; ++f) {
        int ra = wr * 32 + f * 16 + (lane & 15);
        af[f]  = ld_bf8(lat + ra * 64 + ((cc ^ (ra & 7)) << 3));
        int rb = wc * 32 + f * 16 + (lane & 15);
        bfr[f] = ld_bf8(lbt + rb * 64 + ((cc ^ (rb & 7)) << 3));
      }
      #pragma unroll
      for (int fr = 0; fr < 2; ++fr)
        #pragma unroll
        for (int fc = 0; fc < 2; ++fc)
          acc[fr][fc] = mfma16(af[fr], bfr[fc], acc[fr][fc]);
    }
    __syncthreads();
  }
  #pragma unroll
  for (int fr = 0; fr < 2; ++fr) {
    const int mbase = m0 + wr * 32 + fr * 16 + ((lane >> 4) << 2);
    #pragma unroll
    for (int fc = 0; fc < 2; ++fc) {
      const int col = n0 + wc * 32 + fc * 16 + (lane & 15);
      const float bias = bO[col];
      float* dst = out + (size_t)mbase * DMODEL + col;
      #pragma unroll
      for (int r = 0; r < 4; ++r) dst[(size_t)r * DMODEL] = acc[fr][fc][r] + bias;
    }
  }
}

// ------------------------------------------------------------ attention v14
// = v13 with the PV d-range bug fixed: O^T per head is d=64 rows, so PV uses
// TWO accumulators (d-halves 0-31 / 32-63) and 4 PV MFMAs per 32-k tile
// (2 P-frags x 2 d-halves). v12/v13 computed only d<32 (half the output was
// never written -> absmax 1.87e-2 = max|O| of the zeroed half).
__global__ __launch_bounds__(768, 3) void attn_kernel(
    const u16* __restrict__ Q, const u16* __restrict__ K,
    const u16* __restrict__ Vt, const float* __restrict__ table,
    u16* __restrict__ O) {
  // LDS carve:
  //  [0, 12288)      bf16 bias rb2[2][3072] (rev, log2 domain)
  //  [12288, 45056)  kbuf: (hf*2+b)*8192 B   (dead after loop -> combine scratch)
  //  [45056, 77824)  vbuf: same indexing
  __shared__ __align__(16) char smem[77824];
  u16* rb2k = (u16*)smem;
  const int tid = threadIdx.x, lane = tid & 63, w = tid >> 6;
  const int bid = blockIdx.x;
  const int xcd = bid & 7, idx = bid >> 3;        // idx in [0,32)
  const int bh  = xcd * 4 + (idx & 3);
  const int qt  = idx >> 2;                       // [0,8)
  const int h   = bh & (NHEAD - 1);
  for (int t = tid; t < 2 * 3072; t += 768) {
    const int c = (t >= 3072) ? 1 : 0;
    const int x = t - c * 3072;
    int src = 2558 - (x + c);
    src = src < 0 ? 0 : (src > 2046 ? 2046 : src);
    rb2k[c * 3072 + x] = f2bf(table[(size_t)src * NHEAD + h] * 1.4426950408889634f);
  }

  const int lo32 = lane & 31, hi = lane >> 5;
  const int ws = (w < 6) ? w : (w - 6);           // q-tile index [0,6)
  const int hf = (w < 6) ? 0 : 1;                 // k-half
  const int kbase = hf * 768;
  const int q  = qt * 192 + ws * 32 + lo32;       // this lane's q column
  const u16* Qb = Q  + (size_t)bh * NSEQ * HD;
  const u16* Kb = K  + (size_t)bh * NSEQ * HD;
  const u16* Vb = Vt + (size_t)bh * HD * NSEQ;

  // staging: per half, first 256 threads move 64x64 K + 64x64 V per kt.
  const int tloc = tid - hf * 384;                // [0,384) within half
  u16* kl0 = (u16*)(smem + 12288) + hf * 2 * 4096;
  u16* vl0 = (u16*)(smem + 45056) + hf * 2 * 4096;
#define STAGE(b, k0loc)                                                       \
  if (tloc < 256) {                                                           \
    _Pragma("unroll")                                                         \
    for (int i = 0; i < 2; ++i) {                                             \
      int ch = tloc + 256 * i;                                                \
      int row = ch >> 3, pc = ch & 7;                                         \
      int col = (pc ^ (row & 7)) << 3;                                        \
      gload_lds16(Kb + (size_t)(kbase + (k0loc) + row) * HD + col,            \
                  kl0 + (size_t)(b) * 4096 + ch * 8);                         \
      gload_lds16(Vb + (size_t)row * NSEQ + kbase + (k0loc) + col,            \
                  vl0 + (size_t)(b) * 4096 + ch * 8);                         \
    }                                                                         \
  }

  // Q B-frags (register resident): col=q, d = ds*16 + 8*hi + j
  bf16x8 qf[4];
  #pragma unroll
  for (int ds = 0; ds < 4; ++ds)
    qf[ds] = ld_bf8(Qb + (size_t)q * HD + ds * 16 + hi * 8);

  float l_part = 0.f;
  f32x16 acc[2] = {};                             // O^T d-halves: d = dh*32 + rowpat

  const int rswz = lo32 & 7;
  // bias: t = T0 + (kt*64 + ktile*32) + 8*grp + idx
  const int T0  = 1535 - q + 4 * hi + kbase;
  const int c2  = T0 & 1;
  const int dwb = (T0 - c2) >> 1;
  const uint32_t* rbp32 = (const uint32_t*)(rb2k + c2 * 3072);
  const float c1 = 0.125f * 1.4426950408889634f;  // scale * log2(e)

  STAGE(0, 0);
  __syncthreads();
  int cur = 0;

  for (int kt = 0; kt < 12; ++kt) {
    const int nxt = cur ^ 1;
    if (kt < 11) {
      STAGE(nxt, (kt + 1) * 64);
      asm volatile("s_waitcnt vmcnt(4)" ::: "memory");
    } else {
      asm volatile("s_waitcnt vmcnt(0)" ::: "memory");
    }
    __builtin_amdgcn_s_barrier();        // stage(kt) visible; stage(kt+1) in flight
    const u16* kb = (u16*)(smem + 12288) + (hf * 2 + cur) * 4096;
    const u16* vb = (u16*)(smem + 45056) + (hf * 2 + cur) * 4096;
    #pragma unroll
    for (int ktile = 0; ktile < 2; ++ktile) {
      // ---- QK^T swapped: S^T[k][q], A=K rows k, B=Q cols q
      f32x16 st = {};
      __builtin_amdgcn_s_setprio(1);
      #pragma unroll
      for (int ds = 0; ds < 4; ++ds) {
        const int row = ktile * 32 + lo32;
        const bf16x8 kf = ld_bf8(kb + row * 64 + (((2 * ds + hi) ^ rswz) << 3));
        st = mfma32(kf, qf[ds], st);
      }
      __builtin_amdgcn_s_setprio(0);
      // ---- bias (4 groups of 4 consecutive) + exp2 + l
      const int dwk = dwb + ((kt * 64 + ktile * 32) >> 1);
      float bv[4][4];
      #pragma unroll
      for (int gp = 0; gp < 4; ++gp) {
        const uint32_t u0 = rbp32[dwk + 4 * gp];
        const uint32_t u1 = rbp32[dwk + 4 * gp + 1];
        bv[gp][0] = bflo(u0); bv[gp][1] = bfhi(u0);
        bv[gp][2] = bflo(u1); bv[gp][3] = bfhi(u1);
      }
      #pragma unroll
      for (int r = 0; r < 16; ++r) {
        float p = exp2_raw(__builtin_fmaf(st[r], c1, bv[r >> 2][r & 3]));
        st[r] = p;
        l_part += p;
      }
      // ---- pack + permlane swaps -> two PV B-frags (in-register)
      uint32_t wv[8];
      #pragma unroll
      for (int i = 0; i < 8; ++i) wv[i] = pkbf(st[2 * i], st[2 * i + 1]);
      plswap(wv[0], wv[2], hi);  plswap(wv[1], wv[3], hi);
      plswap(wv[4], wv[6], hi);  plswap(wv[5], wv[7], hi);
      i32x4 b0; b0[0] = (int)wv[0]; b0[1] = (int)wv[1]; b0[2] = (int)wv[2]; b0[3] = (int)wv[3];
      i32x4 b1; b1[0] = (int)wv[4]; b1[1] = (int)wv[5]; b1[2] = (int)wv[6]; b1[3] = (int)wv[7];
      const bf16x8 pb0 = __builtin_bit_cast(bf16x8, b0);
      const bf16x8 pb1 = __builtin_bit_cast(bf16x8, b1);
      // ---- PV: A = V^T (rows d, TWO d-halves), B = P
      __builtin_amdgcn_s_setprio(1);
      #pragma unroll
      for (int dh = 0; dh < 2; ++dh) {
        const int vrow = dh * 32 + lo32;         // d; (vrow&7)==rswz
        const bf16x8 va0 = ld_bf8(vb + vrow * 64 + (((4 * ktile + 0 + hi) ^ rswz) << 3));
        acc[dh] = mfma32(va0, pb0, acc[dh]);
        const bf16x8 va1 = ld_bf8(vb + vrow * 64 + (((4 * ktile + 2 + hi) ^ rswz) << 3));
        acc[dh] = mfma32(va1, pb1, acc[dh]);
      }
      __builtin_amdgcn_s_setprio(0);
    }
    __builtin_amdgcn_s_barrier();        // reads of buf[cur] done before overwrite
    cur = nxt;
  }
  // ---- combine halves (no-max partials are additive); scratch = dead kbuf
  // per qtile: 2 dh x 4 f32x4 x 64 lanes + 64 l = 8448 B; 6 x 8448 = 50688 B
  float* scr = (float*)(smem + 12288);
  if (hf == 1) {
    float* wb = scr + ws * 2112;
    #pragma unroll
    for (int dh = 0; dh < 2; ++dh)
      #pragma unroll
      for (int i = 0; i < 4; ++i) {
        f32x4 c4; c4[0] = acc[dh][4*i]; c4[1] = acc[dh][4*i+1];
        c4[2] = acc[dh][4*i+2]; c4[3] = acc[dh][4*i+3];
        ((f32x4*)wb)[(dh * 4 + i) * 64 + lane] = c4;
      }
    wb[2048 + lane] = l_part;
  }
  __syncthreads();
  if (hf == 0) {
    const float* rb = scr + ws * 2112;
    #pragma unroll
    for (int dh = 0; dh < 2; ++dh)
      #pragma unroll
      for (int i = 0; i < 4; ++i) {
        const f32x4 c4 = ((const f32x4*)rb)[(dh * 4 + i) * 64 + lane];
        acc[dh][4*i] += c4[0]; acc[dh][4*i+1] += c4[1];
        acc[dh][4*i+2] += c4[2]; acc[dh][4*i+3] += c4[3];
      }
    l_part += rb[2048 + lane];
    float l_r = l_part + __shfl_xor(l_part, 32);
    const float inv = 1.0f / l_r;
    const int b = bh >> 3;
    u16* orow = O + ((size_t)(b * NSEQ + q)) * DMODEL + h * HD;
    #pragma unroll
    for (int dh = 0; dh < 2; ++dh)
      #pragma unroll
      for (int gp = 0; gp < 4; ++gp) {
        uint2 o4;
        o4.x = pkbf(acc[dh][4*gp]   * inv, acc[dh][4*gp+1] * inv);
        o4.y = pkbf(acc[dh][4*gp+2] * inv, acc[dh][4*gp+3] * inv);
        *(uint2*)(orow + dh * 32 + 8 * gp + 4 * hi) = o4;  // d = dh*32+8gp+4hi+(0..3)
      }
  }
#undef STAGE
}

// ---------------------------------------------------------------- launch
extern "C" void kernel_launch(void* const* d_in, const int* in_sizes, int n_in,
                              void* d_out, int out_size, void* d_ws, size_t ws_size,
                              hipStream_t stream) {
  const float* vis   = (const float*)d_in[0];
  const float* txt   = (const float*)d_in[1];
  const float* WQ    = (const float*)d_in[2];
  const float* bQ    = (const float*)d_in[3];
  const float* WK    = (const float*)d_in[4];
  const float* bK    = (const float*)d_in[5];
  const float* WV    = (const float*)d_in[6];
  const float* bV    = (const float*)d_in[7];
  const float* WO    = (const float*)d_in[8];
  const float* bO    = (const float*)d_in[9];
  const float* table = (const float*)d_in[10];
  const float* gamma = (const float*)d_in[11];
  const float* beta  = (const float*)d_in[12];
  float* out = (float*)d_out;

  char* p = (char*)d_ws;
  u16* zn    = (u16*)p; p += (size_t)NM * DMODEL * 2;
  u16* wqkvt = (u16*)p; p += (size_t)3 * DMODEL * DMODEL * 2;
  u16* wot   = (u16*)p; p += (size_t)DMODEL * DMODEL * 2;
  u16* q     = (u16*)p; p += (size_t)NM * DMODEL * 2;
  u16* k     = (u16*)p; p += (size_t)NM * DMODEL * 2;
  u16* vt    = (u16*)p; p += (size_t)NM * DMODEL * 2;
  u16* o     = (u16*)p; p += (size_t)NM * DMODEL * 2;

  hipLaunchKernelGGL(ln_kernel, dim3(NM / 4), dim3(256), 0, stream,
                     vis, txt, gamma, beta, zn);
  hipLaunchKernelGGL(wtrans_kernel, dim3(16, 16, 4), dim3(256), 0, stream,
                     WQ, WK, WV, WO, wqkvt, wot);
  hipLaunchKernelGGL(gemm_qkv, dim3(16, 48), dim3(256), 0, stream,
                     zn, wqkvt, bQ, bK, bV, q, k, vt);
  hipLaunchKernelGGL(attn_kernel, dim3(256), dim3(768), 0, stream,
                     q, k, vt, table, o);
  hipLaunchKernelGGL(gemm_oproj, dim3(8, 96), dim3(256), 0, stream,
                     o, wot, bO, out);
}

// Round 15
// 75.439 us; speedup vs baseline: 1.2066x; 1.0869x over previous
//
#include <hip/hip_runtime.h>
#include <stdint.h>

#define NSEQ   1536
#define NBATCH 4
#define NM     (NBATCH * NSEQ)   // 6144
#define DMODEL 512
#define NHEAD  8
#define HD     64
#define TBLN   2047              // 2*1024-1

typedef __attribute__((ext_vector_type(4)))  float f32x4;
typedef __attribute__((ext_vector_type(16))) float f32x16;
typedef __attribute__((ext_vector_type(4)))  int   i32x4;
typedef __attribute__((ext_vector_type(2)))  unsigned u32x2;
typedef __attribute__((ext_vector_type(8)))  __bf16 bf16x8;
typedef unsigned short u16;

static_assert(sizeof(bf16x8) == 16, "bf16x8 must be 16B");

__device__ inline u16 f2bf(float f) {
  union { float f; uint32_t u; } v; v.f = f;
  uint32_t u = v.u;
  return (u16)((u + 0x7fffu + ((u >> 16) & 1u)) >> 16);   // RNE
}

__device__ inline bf16x8 ld_bf8(const u16* p) {
  i32x4 v = *(const i32x4*)p;
  return __builtin_bit_cast(bf16x8, v);
}

__device__ inline f32x4 mfma16(bf16x8 a, bf16x8 b, f32x4 c) {
  return __builtin_amdgcn_mfma_f32_16x16x32_bf16(a, b, c, 0, 0, 0);
}

__device__ inline f32x16 mfma32(bf16x8 a, bf16x8 b, f32x16 c) {
  return __builtin_amdgcn_mfma_f32_32x32x16_bf16(a, b, c, 0, 0, 0);
}

__device__ inline void gload_lds16(const void* g, void* l) {
  __builtin_amdgcn_global_load_lds(
      (__attribute__((address_space(1))) void*)(g),
      (__attribute__((address_space(3))) void*)(l), 16, 0, 0);
}

__device__ inline uint32_t pkbf(float a, float b) {
  uint32_t r;
  asm("v_cvt_pk_bf16_f32 %0, %1, %2" : "=v"(r) : "v"(a), "v"(b));
  return r;   // lo16 = bf16(a), hi16 = bf16(b)
}

// Exchange halves across the lane<32 / lane>=32 split between two words.
__device__ inline void plswap(uint32_t& a, uint32_t& b, int hi) {
#if __has_builtin(__builtin_amdgcn_permlane32_swap)
  u32x2 r = __builtin_amdgcn_permlane32_swap(a, b, false, false);
  a = r[0]; b = r[1];
#else
  const uint32_t as = (uint32_t)__shfl_xor((int)a, 32);
  const uint32_t bs = (uint32_t)__shfl_xor((int)b, 32);
  const uint32_t na = hi ? bs : a;   // [a_lo | b_lo]
  const uint32_t nb = hi ? b : as;   // [a_hi | b_hi]
  a = na; b = nb;
#endif
}

__device__ inline float exp2_raw(float x) {   // |x| small: no libm guards
  float r;
  asm("v_exp_f32 %0, %1" : "=v"(r) : "v"(x));
  return r;
}

__device__ inline float bfhi(uint32_t u) {
  union { uint32_t u; float f; } v; v.u = u & 0xffff0000u; return v.f;
}
__device__ inline float bflo(uint32_t u) {
  union { uint32_t u; float f; } v; v.u = u << 16; return v.f;
}

// ---------------------------------------------------------------- LayerNorm
__global__ __launch_bounds__(256) void ln_kernel(
    const float* __restrict__ vis, const float* __restrict__ txt,
    const float* __restrict__ gamma, const float* __restrict__ beta,
    u16* __restrict__ zn) {
  const int lane = threadIdx.x & 63;
  const int row  = blockIdx.x * 4 + (threadIdx.x >> 6);
  const int b = row / NSEQ, n = row - b * NSEQ;
  const float* src = (n < 1024) ? (vis + ((size_t)b * 1024 + n) * DMODEL)
                                : (txt + ((size_t)b * 512 + (n - 1024)) * DMODEL);
  const float4* s4 = (const float4*)src;
  float4 x0 = s4[lane], x1 = s4[lane + 64];
  float s = x0.x + x0.y + x0.z + x0.w + x1.x + x1.y + x1.z + x1.w;
  float q = x0.x*x0.x + x0.y*x0.y + x0.z*x0.z + x0.w*x0.w
          + x1.x*x1.x + x1.y*x1.y + x1.z*x1.z + x1.w*x1.w;
  #pragma unroll
  for (int m = 1; m < 64; m <<= 1) { s += __shfl_xor(s, m); q += __shfl_xor(q, m); }
  const float mean = s * (1.0f / 512.0f);
  const float var  = q * (1.0f / 512.0f) - mean * mean;
  const float rstd = rsqrtf(var + 1e-5f);
  const float4* g4 = (const float4*)gamma;
  const float4* b4 = (const float4*)beta;
  float4 g0 = g4[lane], g1 = g4[lane + 64], p0 = b4[lane], p1 = b4[lane + 64];
  u16* dst = zn + (size_t)row * DMODEL;
  ushort4 o0, o1;
  o0.x = f2bf((x0.x - mean) * rstd * g0.x + p0.x);
  o0.y = f2bf((x0.y - mean) * rstd * g0.y + p0.y);
  o0.z = f2bf((x0.z - mean) * rstd * g0.z + p0.z);
  o0.w = f2bf((x0.w - mean) * rstd * g0.w + p0.w);
  o1.x = f2bf((x1.x - mean) * rstd * g1.x + p1.x);
  o1.y = f2bf((x1.y - mean) * rstd * g1.y + p1.y);
  o1.z = f2bf((x1.z - mean) * rstd * g1.z + p1.z);
  o1.w = f2bf((x1.w - mean) * rstd * g1.w + p1.w);
  *(ushort4*)(dst + lane * 4)        = o0;
  *(ushort4*)(dst + (lane + 64) * 4) = o1;
}

// ------------------------------------------------- weight transpose -> bf16
__global__ __launch_bounds__(256) void wtrans_kernel(
    const float* __restrict__ WQ, const float* __restrict__ WK,
    const float* __restrict__ WV, const float* __restrict__ WO,
    u16* __restrict__ wqkvt, u16* __restrict__ wot) {
  __shared__ float t[32][33];
  const int m = blockIdx.z;
  const float* W = (m == 0) ? WQ : (m == 1) ? WK : (m == 2) ? WV : WO;
  const int n0 = blockIdx.x * 32, k0 = blockIdx.y * 32;
  const int tx = threadIdx.x & 31, ty = threadIdx.x >> 5;
  #pragma unroll
  for (int j = 0; j < 4; ++j)
    t[ty + j * 8][tx] = W[(size_t)(k0 + ty + j * 8) * DMODEL + n0 + tx];
  __syncthreads();
  u16* out = (m < 3) ? (wqkvt + (size_t)m * DMODEL * DMODEL) : wot;
  #pragma unroll
  for (int j = 0; j < 4; ++j)
    out[(size_t)(n0 + ty + j * 8) * DMODEL + k0 + tx] = f2bf(t[tx][ty + j * 8]);
}

// ------------------------------------------------------------- QKV GEMM v2
// 192(M) x 96(N) tile, BK=64, 4 waves (2x2), wave tile 96x48.
// grid 32x16 = 512 blocks = exactly 2/CU. Double-buffered LDS (72 KB),
// counted vmcnt(9) + two arrival barriers per kt (v9/v14-validated pattern).
__global__ __launch_bounds__(256, 2) void gemm_qkv(
    const u16* __restrict__ A, const u16* __restrict__ Bt,
    const float* __restrict__ bQ, const float* __restrict__ bK, const float* __restrict__ bV,
    u16* __restrict__ Q, u16* __restrict__ Kk, u16* __restrict__ Vt) {
  __shared__ __align__(16) u16 lat[2][192 * 64];  // 48 KB
  __shared__ __align__(16) u16 lbt[2][96 * 64];   // 24 KB
  const int tid = threadIdx.x, lane = tid & 63, w = tid >> 6;
  const int wr = w >> 1, wc = w & 1;
  const int m0 = blockIdx.y * 192, n0 = blockIdx.x * 96;
  f32x4 acc[6][3] = {};
#define QSTAGE(buf, k0)                                                        \
  do {                                                                         \
    _Pragma("unroll")                                                          \
    for (int i = 0; i < 6; ++i) {                                              \
      int ch = tid + 256 * i;                      /* A: 1536 chunks */        \
      int row = ch >> 3, pc = ch & 7;                                          \
      int kk = (k0) + ((pc ^ (row & 7)) << 3);                                 \
      gload_lds16(A + (size_t)(m0 + row) * DMODEL + kk, lat[buf] + (size_t)ch * 8); \
    }                                                                          \
    _Pragma("unroll")                                                          \
    for (int i = 0; i < 3; ++i) {                                              \
      int ch = tid + 256 * i;                      /* B: 768 chunks */         \
      int row = ch >> 3, pc = ch & 7;                                          \
      int kk = (k0) + ((pc ^ (row & 7)) << 3);                                 \
      gload_lds16(Bt + (size_t)(n0 + row) * DMODEL + kk, lbt[buf] + (size_t)ch * 8); \
    }                                                                          \
  } while (0)

  QSTAGE(0, 0);
  __syncthreads();
  int cur = 0;
  for (int kt = 0; kt < 8; ++kt) {
    const int nxt = cur ^ 1;
    if (kt < 7) {
      QSTAGE(nxt, (kt + 1) * 64);
      asm volatile("s_waitcnt vmcnt(9)" ::: "memory");
    } else {
      asm volatile("s_waitcnt vmcnt(0)" ::: "memory");
    }
    __builtin_amdgcn_s_barrier();
    #pragma unroll
    for (int ks = 0; ks < 2; ++ks) {
      bf16x8 af[6], bfr[3];
      const int cc = ks * 4 + (lane >> 4);
      #pragma unroll
      for (int f = 0; f < 6; ++f) {
        int ra = wr * 96 + f * 16 + (lane & 15);
        af[f]  = ld_bf8(lat[cur] + ra * 64 + ((cc ^ (ra & 7)) << 3));
      }
      #pragma unroll
      for (int f = 0; f < 3; ++f) {
        int rb = wc * 48 + f * 16 + (lane & 15);
        bfr[f] = ld_bf8(lbt[cur] + rb * 64 + ((cc ^ (rb & 7)) << 3));
      }
      __builtin_amdgcn_s_setprio(1);
      #pragma unroll
      for (int fr = 0; fr < 6; ++fr)
        #pragma unroll
        for (int fc = 0; fc < 3; ++fc)
          acc[fr][fc] = mfma16(af[fr], bfr[fc], acc[fr][fc]);
      __builtin_amdgcn_s_setprio(0);
    }
    __builtin_amdgcn_s_barrier();
    cur = nxt;
  }
  #pragma unroll
  for (int fr = 0; fr < 6; ++fr) {
    const int mbase = m0 + wr * 96 + fr * 16 + ((lane >> 4) << 2);
    const int b = mbase / NSEQ;
    const int nseq = mbase - b * NSEQ;
    #pragma unroll
    for (int fc = 0; fc < 3; ++fc) {
      const int col = n0 + wc * 48 + fc * 16 + (lane & 15);
      const int which = col >> 9;
      const int cw = col & 511;
      const int h = cw >> 6, d = cw & 63;
      const float bias = (which == 0) ? bQ[cw] : (which == 1) ? bK[cw] : bV[cw];
      if (which < 2) {
        u16* dst = ((which == 0) ? Q : Kk) + ((size_t)(b * NHEAD + h) * NSEQ + nseq) * HD + d;
        #pragma unroll
        for (int r = 0; r < 4; ++r) dst[(size_t)r * HD] = f2bf(acc[fr][fc][r] + bias);
      } else {
        ushort4 pv;
        pv.x = f2bf(acc[fr][fc][0] + bias);
        pv.y = f2bf(acc[fr][fc][1] + bias);
        pv.z = f2bf(acc[fr][fc][2] + bias);
        pv.w = f2bf(acc[fr][fc][3] + bias);
        *(ushort4*)(Vt + ((size_t)(b * NHEAD + h) * HD + d) * NSEQ + nseq) = pv;
      }
    }
  }
#undef QSTAGE
}

// ------------------------------------------------------------ O-proj GEMM v2
// 96x64 tile, 4 waves (2x2), wave tile 48x32. grid 8x64 = 512 blocks (2/CU).
// Double-buffered (40 KB), counted vmcnt(5) + two arrival barriers per kt.
__global__ __launch_bounds__(256, 2) void gemm_oproj(
    const u16* __restrict__ A, const u16* __restrict__ Bt,
    const float* __restrict__ bO, float* __restrict__ out) {
  __shared__ __align__(16) u16 lat[2][96 * 64];   // 24 KB
  __shared__ __align__(16) u16 lbt[2][64 * 64];   // 16 KB
  const int tid = threadIdx.x, lane = tid & 63, w = tid >> 6;
  const int wr = w >> 1, wc = w & 1;
  const int m0 = blockIdx.y * 96, n0 = blockIdx.x * 64;
  f32x4 acc[3][2] = {};
#define OSTAGE(buf, k0)                                                        \
  do {                                                                         \
    _Pragma("unroll")                                                          \
    for (int i = 0; i < 3; ++i) {                                              \
      int ch = tid + 256 * i;                      /* A: 768 chunks */         \
      int row = ch >> 3, pc = ch & 7;                                          \
      int kk = (k0) + ((pc ^ (row & 7)) << 3);                                 \
      gload_lds16(A + (size_t)(m0 + row) * DMODEL + kk, lat[buf] + (size_t)ch * 8); \
    }                                                                          \
    _Pragma("unroll")                                                          \
    for (int i = 0; i < 2; ++i) {                                              \
      int ch = tid + 256 * i;                      /* B: 512 chunks */         \
      int row = ch >> 3, pc = ch & 7;                                          \
      int kk = (k0) + ((pc ^ (row & 7)) << 3);                                 \
      gload_lds16(Bt + (size_t)(n0 + row) * DMODEL + kk, lbt[buf] + (size_t)ch * 8); \
    }                                                                          \
  } while (0)

  OSTAGE(0, 0);
  __syncthreads();
  int cur = 0;
  for (int kt = 0; kt < 8; ++kt) {
    const int nxt = cur ^ 1;
    if (kt < 7) {
      OSTAGE(nxt, (kt + 1) * 64);
      asm volatile("s_waitcnt vmcnt(5)" ::: "memory");
    } else {
      asm volatile("s_waitcnt vmcnt(0)" ::: "memory");
    }
    __builtin_amdgcn_s_barrier();
    #pragma unroll
    for (int ks = 0; ks < 2; ++ks) {
      bf16x8 af[3], bfr[2];
      const int cc = ks * 4 + (lane >> 4);
      #pragma unroll
      for (int f = 0; f < 3; ++f) {
        int ra = wr * 48 + f * 16 + (lane & 15);
        af[f]  = ld_bf8(lat[cur] + ra * 64 + ((cc ^ (ra & 7)) << 3));
      }
      #pragma unroll
      for (int f = 0; f < 2; ++f) {
        int rb = wc * 32 + f * 16 + (lane & 15);
        bfr[f] = ld_bf8(lbt[cur] + rb * 64 + ((cc ^ (rb & 7)) << 3));
      }
      __builtin_amdgcn_s_setprio(1);
      #pragma unroll
      for (int fr = 0; fr < 3; ++fr)
        #pragma unroll
        for (int fc = 0; fc < 2; ++fc)
          acc[fr][fc] = mfma16(af[fr], bfr[fc], acc[fr][fc]);
      __builtin_amdgcn_s_setprio(0);
    }
    __builtin_amdgcn_s_barrier();
    cur = nxt;
  }
  #pragma unroll
  for (int fr = 0; fr < 3; ++fr) {
    const int mbase = m0 + wr * 48 + fr * 16 + ((lane >> 4) << 2);
    #pragma unroll
    for (int fc = 0; fc < 2; ++fc) {
      const int col = n0 + wc * 32 + fc * 16 + (lane & 15);
      const float bias = bO[col];
      float* dst = out + (size_t)mbase * DMODEL + col;
      #pragma unroll
      for (int r = 0; r < 4; ++r) dst[(size_t)r * DMODEL] = acc[fr][fc][r] + bias;
    }
  }
#undef OSTAGE
}

// ------------------------------------------------------------ attention v14
// (unchanged, validated R14): 32x32 MFMA, swapped QK^T, in-register P via
// cvt_pk + permlane32_swap, TWO d-half accumulators, 12 waves = 6 q-tiles x
// 2 k-halves with additive no-max partials, dbuf + counted vmcnt(4).
__global__ __launch_bounds__(768, 3) void attn_kernel(
    const u16* __restrict__ Q, const u16* __restrict__ K,
    const u16* __restrict__ Vt, const float* __restrict__ table,
    u16* __restrict__ O) {
  __shared__ __align__(16) char smem[77824];
  u16* rb2k = (u16*)smem;
  const int tid = threadIdx.x, lane = tid & 63, w = tid >> 6;
  const int bid = blockIdx.x;
  const int xcd = bid & 7, idx = bid >> 3;
  const int bh  = xcd * 4 + (idx & 3);
  const int qt  = idx >> 2;
  const int h   = bh & (NHEAD - 1);
  for (int t = tid; t < 2 * 3072; t += 768) {
    const int c = (t >= 3072) ? 1 : 0;
    const int x = t - c * 3072;
    int src = 2558 - (x + c);
    src = src < 0 ? 0 : (src > 2046 ? 2046 : src);
    rb2k[c * 3072 + x] = f2bf(table[(size_t)src * NHEAD + h] * 1.4426950408889634f);
  }

  const int lo32 = lane & 31, hi = lane >> 5;
  const int ws = (w < 6) ? w : (w - 6);
  const int hf = (w < 6) ? 0 : 1;
  const int kbase = hf * 768;
  const int q  = qt * 192 + ws * 32 + lo32;
  const u16* Qb = Q  + (size_t)bh * NSEQ * HD;
  const u16* Kb = K  + (size_t)bh * NSEQ * HD;
  const u16* Vb = Vt + (size_t)bh * HD * NSEQ;

  const int tloc = tid - hf * 384;
  u16* kl0 = (u16*)(smem + 12288) + hf * 2 * 4096;
  u16* vl0 = (u16*)(smem + 45056) + hf * 2 * 4096;
#define STAGE(b, k0loc)                                                       \
  if (tloc < 256) {                                                           \
    _Pragma("unroll")                                                         \
    for (int i = 0; i < 2; ++i) {                                             \
      int ch = tloc + 256 * i;                                                \
      int row = ch >> 3, pc = ch & 7;                                         \
      int col = (pc ^ (row & 7)) << 3;                                        \
      gload_lds16(Kb + (size_t)(kbase + (k0loc) + row) * HD + col,            \
                  kl0 + (size_t)(b) * 4096 + ch * 8);                         \
      gload_lds16(Vb + (size_t)row * NSEQ + kbase + (k0loc) + col,            \
                  vl0 + (size_t)(b) * 4096 + ch * 8);                         \
    }                                                                         \
  }

  bf16x8 qf[4];
  #pragma unroll
  for (int ds = 0; ds < 4; ++ds)
    qf[ds] = ld_bf8(Qb + (size_t)q * HD + ds * 16 + hi * 8);

  float l_part = 0.f;
  f32x16 acc[2] = {};

  const int rswz = lo32 & 7;
  const int T0  = 1535 - q + 4 * hi + kbase;
  const int c2  = T0 & 1;
  const int dwb = (T0 - c2) >> 1;
  const uint32_t* rbp32 = (const uint32_t*)(rb2k + c2 * 3072);
  const float c1 = 0.125f * 1.4426950408889634f;

  STAGE(0, 0);
  __syncthreads();
  int cur = 0;

  for (int kt = 0; kt < 12; ++kt) {
    const int nxt = cur ^ 1;
    if (kt < 11) {
      STAGE(nxt, (kt + 1) * 64);
      asm volatile("s_waitcnt vmcnt(4)" ::: "memory");
    } else {
      asm volatile("s_waitcnt vmcnt(0)" ::: "memory");
    }
    __builtin_amdgcn_s_barrier();
    const u16* kb = (u16*)(smem + 12288) + (hf * 2 + cur) * 4096;
    const u16* vb = (u16*)(smem + 45056) + (hf * 2 + cur) * 4096;
    #pragma unroll
    for (int ktile = 0; ktile < 2; ++ktile) {
      f32x16 st = {};
      __builtin_amdgcn_s_setprio(1);
      #pragma unroll
      for (int ds = 0; ds < 4; ++ds) {
        const int row = ktile * 32 + lo32;
        const bf16x8 kf = ld_bf8(kb + row * 64 + (((2 * ds + hi) ^ rswz) << 3));
        st = mfma32(kf, qf[ds], st);
      }
      __builtin_amdgcn_s_setprio(0);
      const int dwk = dwb + ((kt * 64 + ktile * 32) >> 1);
      float bv[4][4];
      #pragma unroll
      for (int gp = 0; gp < 4; ++gp) {
        const uint32_t u0 = rbp32[dwk + 4 * gp];
        const uint32_t u1 = rbp32[dwk + 4 * gp + 1];
        bv[gp][0] = bflo(u0); bv[gp][1] = bfhi(u0);
        bv[gp][2] = bflo(u1); bv[gp][3] = bfhi(u1);
      }
      #pragma unroll
      for (int r = 0; r < 16; ++r) {
        float p = exp2_raw(__builtin_fmaf(st[r], c1, bv[r >> 2][r & 3]));
        st[r] = p;
        l_part += p;
      }
      uint32_t wv[8];
      #pragma unroll
      for (int i = 0; i < 8; ++i) wv[i] = pkbf(st[2 * i], st[2 * i + 1]);
      plswap(wv[0], wv[2], hi);  plswap(wv[1], wv[3], hi);
      plswap(wv[4], wv[6], hi);  plswap(wv[5], wv[7], hi);
      i32x4 b0; b0[0] = (int)wv[0]; b0[1] = (int)wv[1]; b0[2] = (int)wv[2]; b0[3] = (int)wv[3];
      i32x4 b1; b1[0] = (int)wv[4]; b1[1] = (int)wv[5]; b1[2] = (int)wv[6]; b1[3] = (int)wv[7];
      const bf16x8 pb0 = __builtin_bit_cast(bf16x8, b0);
      const bf16x8 pb1 = __builtin_bit_cast(bf16x8, b1);
      __builtin_amdgcn_s_setprio(1);
      #pragma unroll
      for (int dh = 0; dh < 2; ++dh) {
        const int vrow = dh * 32 + lo32;
        const bf16x8 va0 = ld_bf8(vb + vrow * 64 + (((4 * ktile + 0 + hi) ^ rswz) << 3));
        acc[dh] = mfma32(va0, pb0, acc[dh]);
        const bf16x8 va1 = ld_bf8(vb + vrow * 64 + (((4 * ktile + 2 + hi) ^ rswz) << 3));
        acc[dh] = mfma32(va1, pb1, acc[dh]);
      }
      __builtin_amdgcn_s_setprio(0);
    }
    __builtin_amdgcn_s_barrier();
    cur = nxt;
  }
  float* scr = (float*)(smem + 12288);
  if (hf == 1) {
    float* wb = scr + ws * 2112;
    #pragma unroll
    for (int dh = 0; dh < 2; ++dh)
      #pragma unroll
      for (int i = 0; i < 4; ++i) {
        f32x4 c4; c4[0] = acc[dh][4*i]; c4[1] = acc[dh][4*i+1];
        c4[2] = acc[dh][4*i+2]; c4[3] = acc[dh][4*i+3];
        ((f32x4*)wb)[(dh * 4 + i) * 64 + lane] = c4;
      }
    wb[2048 + lane] = l_part;
  }
  __syncthreads();
  if (hf == 0) {
    const float* rb = scr + ws * 2112;
    #pragma unroll
    for (int dh = 0; dh < 2; ++dh)
      #pragma unroll
      for (int i = 0; i < 4; ++i) {
        const f32x4 c4 = ((const f32x4*)rb)[(dh * 4 + i) * 64 + lane];
        acc[dh][4*i] += c4[0]; acc[dh][4*i+1] += c4[1];
        acc[dh][4*i+2] += c4[2]; acc[dh][4*i+3] += c4[3];
      }
    l_part += rb[2048 + lane];
    float l_r = l_part + __shfl_xor(l_part, 32);
    const float inv = 1.0f / l_r;
    const int b = bh >> 3;
    u16* orow = O + ((size_t)(b * NSEQ + q)) * DMODEL + h * HD;
    #pragma unroll
    for (int dh = 0; dh < 2; ++dh)
      #pragma unroll
      for (int gp = 0; gp < 4; ++gp) {
        uint2 o4;
        o4.x = pkbf(acc[dh][4*gp]   * inv, acc[dh][4*gp+1] * inv);
        o4.y = pkbf(acc[dh][4*gp+2] * inv, acc[dh][4*gp+3] * inv);
        *(uint2*)(orow + dh * 32 + 8 * gp + 4 * hi) = o4;
      }
  }
#undef STAGE
}

// ---------------------------------------------------------------- launch
extern "C" void kernel_launch(void* const* d_in, const int* in_sizes, int n_in,
                              void* d_out, int out_size, void* d_ws, size_t ws_size,
                              hipStream_t stream) {
  const float* vis   = (const float*)d_in[0];
  const float* txt   = (const float*)d_in[1];
  const float* WQ    = (const float*)d_in[2];
  const float* bQ    = (const float*)d_in[3];
  const float* WK    = (const float*)d_in[4];
  const float* bK    = (const float*)d_in[5];
  const float* WV    = (const float*)d_in[6];
  const float* bV    = (const float*)d_in[7];
  const float* WO    = (const float*)d_in[8];
  const float* bO    = (const float*)d_in[9];
  const float* table = (const float*)d_in[10];
  const float* gamma = (const float*)d_in[11];
  const float* beta  = (const float*)d_in[12];
  float* out = (float*)d_out;

  char* p = (char*)d_ws;
  u16* zn    = (u16*)p; p += (size_t)NM * DMODEL * 2;
  u16* wqkvt = (u16*)p; p += (size_t)3 * DMODEL * DMODEL * 2;
  u16* wot   = (u16*)p; p += (size_t)DMODEL * DMODEL * 2;
  u16* q     = (u16*)p; p += (size_t)NM * DMODEL * 2;
  u16* k     = (u16*)p; p += (size_t)NM * DMODEL * 2;
  u16* vt    = (u16*)p; p += (size_t)NM * DMODEL * 2;
  u16* o     = (u16*)p; p += (size_t)NM * DMODEL * 2;

  hipLaunchKernelGGL(ln_kernel, dim3(NM / 4), dim3(256), 0, stream,
                     vis, txt, gamma, beta, zn);
  hipLaunchKernelGGL(wtrans_kernel, dim3(16, 16, 4), dim3(256), 0, stream,
                     WQ, WK, WV, WO, wqkvt, wot);
  hipLaunchKernelGGL(gemm_qkv, dim3(16, 32), dim3(256), 0, stream,
                     zn, wqkvt, bQ, bK, bV, q, k, vt);
  hipLaunchKernelGGL(attn_kernel, dim3(256), dim3(768), 0, stream,
                     q, k, vt, table, o);
  hipLaunchKernelGGL(gemm_oproj, dim3(8, 64), dim3(256), 0, stream,
                     o, wot, bO, out);
}

// Round 16
// 72.803 us; speedup vs baseline: 1.2503x; 1.0362x over previous
//
#include <hip/hip_runtime.h>
#include <stdint.h>

#define NSEQ   1536
#define NBATCH 4
#define NM     (NBATCH * NSEQ)   // 6144
#define DMODEL 512
#define NHEAD  8
#define HD     64
#define TBLN   2047              // 2*1024-1

typedef __attribute__((ext_vector_type(4)))  float f32x4;
typedef __attribute__((ext_vector_type(16))) float f32x16;
typedef __attribute__((ext_vector_type(4)))  int   i32x4;
typedef __attribute__((ext_vector_type(2)))  unsigned u32x2;
typedef __attribute__((ext_vector_type(8)))  __bf16 bf16x8;
typedef unsigned short u16;

static_assert(sizeof(bf16x8) == 16, "bf16x8 must be 16B");

__device__ inline u16 f2bf(float f) {
  union { float f; uint32_t u; } v; v.f = f;
  uint32_t u = v.u;
  return (u16)((u + 0x7fffu + ((u >> 16) & 1u)) >> 16);   // RNE
}

__device__ inline bf16x8 ld_bf8(const u16* p) {
  i32x4 v = *(const i32x4*)p;
  return __builtin_bit_cast(bf16x8, v);
}

__device__ inline f32x4 mfma16(bf16x8 a, bf16x8 b, f32x4 c) {
  return __builtin_amdgcn_mfma_f32_16x16x32_bf16(a, b, c, 0, 0, 0);
}

__device__ inline f32x16 mfma32(bf16x8 a, bf16x8 b, f32x16 c) {
  return __builtin_amdgcn_mfma_f32_32x32x16_bf16(a, b, c, 0, 0, 0);
}

__device__ inline void gload_lds16(const void* g, void* l) {
  __builtin_amdgcn_global_load_lds(
      (__attribute__((address_space(1))) void*)(g),
      (__attribute__((address_space(3))) void*)(l), 16, 0, 0);
}

__device__ inline uint32_t pkbf(float a, float b) {
  uint32_t r;
  asm("v_cvt_pk_bf16_f32 %0, %1, %2" : "=v"(r) : "v"(a), "v"(b));
  return r;   // lo16 = bf16(a), hi16 = bf16(b)
}

// Exchange halves across the lane<32 / lane>=32 split between two words.
__device__ inline void plswap(uint32_t& a, uint32_t& b, int hi) {
#if __has_builtin(__builtin_amdgcn_permlane32_swap)
  u32x2 r = __builtin_amdgcn_permlane32_swap(a, b, false, false);
  a = r[0]; b = r[1];
#else
  const uint32_t as = (uint32_t)__shfl_xor((int)a, 32);
  const uint32_t bs = (uint32_t)__shfl_xor((int)b, 32);
  const uint32_t na = hi ? bs : a;   // [a_lo | b_lo]
  const uint32_t nb = hi ? b : as;   // [a_hi | b_hi]
  a = na; b = nb;
#endif
}

__device__ inline float exp2_raw(float x) {   // |x| small: no libm guards
  float r;
  asm("v_exp_f32 %0, %1" : "=v"(r) : "v"(x));
  return r;
}

__device__ inline float bfhi(uint32_t u) {
  union { uint32_t u; float f; } v; v.u = u & 0xffff0000u; return v.f;
}
__device__ inline float bflo(uint32_t u) {
  union { uint32_t u; float f; } v; v.u = u << 16; return v.f;
}

// ------------------------------------------- fused LayerNorm + W-transpose
// blocks [0,1536): LN rows (4/block). blocks [1536,2560): weight transpose.
__global__ __launch_bounds__(256) void prep_kernel(
    const float* __restrict__ vis, const float* __restrict__ txt,
    const float* __restrict__ gamma, const float* __restrict__ beta,
    const float* __restrict__ WQ, const float* __restrict__ WK,
    const float* __restrict__ WV, const float* __restrict__ WO,
    u16* __restrict__ zn, u16* __restrict__ wqkvt, u16* __restrict__ wot) {
  __shared__ float t[32][33];
  if (blockIdx.x < 1536) {
    const int lane = threadIdx.x & 63;
    const int row  = blockIdx.x * 4 + (threadIdx.x >> 6);
    const int b = row / NSEQ, n = row - b * NSEQ;
    const float* src = (n < 1024) ? (vis + ((size_t)b * 1024 + n) * DMODEL)
                                  : (txt + ((size_t)b * 512 + (n - 1024)) * DMODEL);
    const float4* s4 = (const float4*)src;
    float4 x0 = s4[lane], x1 = s4[lane + 64];
    float s = x0.x + x0.y + x0.z + x0.w + x1.x + x1.y + x1.z + x1.w;
    float q = x0.x*x0.x + x0.y*x0.y + x0.z*x0.z + x0.w*x0.w
            + x1.x*x1.x + x1.y*x1.y + x1.z*x1.z + x1.w*x1.w;
    #pragma unroll
    for (int m = 1; m < 64; m <<= 1) { s += __shfl_xor(s, m); q += __shfl_xor(q, m); }
    const float mean = s * (1.0f / 512.0f);
    const float var  = q * (1.0f / 512.0f) - mean * mean;
    const float rstd = rsqrtf(var + 1e-5f);
    const float4* g4 = (const float4*)gamma;
    const float4* b4 = (const float4*)beta;
    float4 g0 = g4[lane], g1 = g4[lane + 64], p0 = b4[lane], p1 = b4[lane + 64];
    u16* dst = zn + (size_t)row * DMODEL;
    ushort4 o0, o1;
    o0.x = f2bf((x0.x - mean) * rstd * g0.x + p0.x);
    o0.y = f2bf((x0.y - mean) * rstd * g0.y + p0.y);
    o0.z = f2bf((x0.z - mean) * rstd * g0.z + p0.z);
    o0.w = f2bf((x0.w - mean) * rstd * g0.w + p0.w);
    o1.x = f2bf((x1.x - mean) * rstd * g1.x + p1.x);
    o1.y = f2bf((x1.y - mean) * rstd * g1.y + p1.y);
    o1.z = f2bf((x1.z - mean) * rstd * g1.z + p1.z);
    o1.w = f2bf((x1.w - mean) * rstd * g1.w + p1.w);
    *(ushort4*)(dst + lane * 4)        = o0;
    *(ushort4*)(dst + (lane + 64) * 4) = o1;
  } else {
    const int id = blockIdx.x - 1536;             // [0,1024)
    const int m = id & 3;
    const int rem = id >> 2;                      // [0,256)
    const float* W = (m == 0) ? WQ : (m == 1) ? WK : (m == 2) ? WV : WO;
    const int n0 = (rem & 15) * 32, k0 = (rem >> 4) * 32;
    const int tx = threadIdx.x & 31, ty = threadIdx.x >> 5;
    #pragma unroll
    for (int j = 0; j < 4; ++j)
      t[ty + j * 8][tx] = W[(size_t)(k0 + ty + j * 8) * DMODEL + n0 + tx];
    __syncthreads();
    u16* out = (m < 3) ? (wqkvt + (size_t)m * DMODEL * DMODEL) : wot;
    #pragma unroll
    for (int j = 0; j < 4; ++j)
      out[(size_t)(n0 + ty + j * 8) * DMODEL + k0 + tx] = f2bf(t[tx][ty + j * 8]);
  }
}

// ------------------------------------------------------------- QKV GEMM v2
// 192(M) x 96(N) tile, BK=64, 4 waves (2x2), wave tile 96x48.
// grid 32x16 = 512 blocks = exactly 2/CU. Double-buffered LDS (72 KB),
// counted vmcnt(9) + two arrival barriers per kt.
__global__ __launch_bounds__(256, 2) void gemm_qkv(
    const u16* __restrict__ A, const u16* __restrict__ Bt,
    const float* __restrict__ bQ, const float* __restrict__ bK, const float* __restrict__ bV,
    u16* __restrict__ Q, u16* __restrict__ Kk, u16* __restrict__ Vt) {
  __shared__ __align__(16) u16 lat[2][192 * 64];  // 48 KB
  __shared__ __align__(16) u16 lbt[2][96 * 64];   // 24 KB
  const int tid = threadIdx.x, lane = tid & 63, w = tid >> 6;
  const int wr = w >> 1, wc = w & 1;
  const int m0 = blockIdx.y * 192, n0 = blockIdx.x * 96;
  f32x4 acc[6][3] = {};
#define QSTAGE(buf, k0)                                                        \
  do {                                                                         \
    _Pragma("unroll")                                                          \
    for (int i = 0; i < 6; ++i) {                                              \
      int ch = tid + 256 * i;                                                  \
      int row = ch >> 3, pc = ch & 7;                                          \
      int kk = (k0) + ((pc ^ (row & 7)) << 3);                                 \
      gload_lds16(A + (size_t)(m0 + row) * DMODEL + kk, lat[buf] + (size_t)ch * 8); \
    }                                                                          \
    _Pragma("unroll")                                                          \
    for (int i = 0; i < 3; ++i) {                                              \
      int ch = tid + 256 * i;                                                  \
      int row = ch >> 3, pc = ch & 7;                                          \
      int kk = (k0) + ((pc ^ (row & 7)) << 3);                                 \
      gload_lds16(Bt + (size_t)(n0 + row) * DMODEL + kk, lbt[buf] + (size_t)ch * 8); \
    }                                                                          \
  } while (0)

  QSTAGE(0, 0);
  __syncthreads();
  int cur = 0;
  for (int kt = 0; kt < 8; ++kt) {
    const int nxt = cur ^ 1;
    if (kt < 7) {
      QSTAGE(nxt, (kt + 1) * 64);
      asm volatile("s_waitcnt vmcnt(9)" ::: "memory");
    } else {
      asm volatile("s_waitcnt vmcnt(0)" ::: "memory");
    }
    __builtin_amdgcn_s_barrier();
    #pragma unroll
    for (int ks = 0; ks < 2; ++ks) {
      bf16x8 af[6], bfr[3];
      const int cc = ks * 4 + (lane >> 4);
      #pragma unroll
      for (int f = 0; f < 6; ++f) {
        int ra = wr * 96 + f * 16 + (lane & 15);
        af[f]  = ld_bf8(lat[cur] + ra * 64 + ((cc ^ (ra & 7)) << 3));
      }
      #pragma unroll
      for (int f = 0; f < 3; ++f) {
        int rb = wc * 48 + f * 16 + (lane & 15);
        bfr[f] = ld_bf8(lbt[cur] + rb * 64 + ((cc ^ (rb & 7)) << 3));
      }
      __builtin_amdgcn_s_setprio(1);
      #pragma unroll
      for (int fr = 0; fr < 6; ++fr)
        #pragma unroll
        for (int fc = 0; fc < 3; ++fc)
          acc[fr][fc] = mfma16(af[fr], bfr[fc], acc[fr][fc]);
      __builtin_amdgcn_s_setprio(0);
    }
    __builtin_amdgcn_s_barrier();
    cur = nxt;
  }
  #pragma unroll
  for (int fr = 0; fr < 6; ++fr) {
    const int mbase = m0 + wr * 96 + fr * 16 + ((lane >> 4) << 2);
    const int b = mbase / NSEQ;
    const int nseq = mbase - b * NSEQ;
    #pragma unroll
    for (int fc = 0; fc < 3; ++fc) {
      const int col = n0 + wc * 48 + fc * 16 + (lane & 15);
      const int which = col >> 9;
      const int cw = col & 511;
      const int h = cw >> 6, d = cw & 63;
      const float bias = (which == 0) ? bQ[cw] : (which == 1) ? bK[cw] : bV[cw];
      if (which < 2) {
        u16* dst = ((which == 0) ? Q : Kk) + ((size_t)(b * NHEAD + h) * NSEQ + nseq) * HD + d;
        #pragma unroll
        for (int r = 0; r < 4; ++r) dst[(size_t)r * HD] = f2bf(acc[fr][fc][r] + bias);
      } else {
        ushort4 pv;
        pv.x = f2bf(acc[fr][fc][0] + bias);
        pv.y = f2bf(acc[fr][fc][1] + bias);
        pv.z = f2bf(acc[fr][fc][2] + bias);
        pv.w = f2bf(acc[fr][fc][3] + bias);
        *(ushort4*)(Vt + ((size_t)(b * NHEAD + h) * HD + d) * NSEQ + nseq) = pv;
      }
    }
  }
#undef QSTAGE
}

// ------------------------------------------------------------ O-proj GEMM v2
__global__ __launch_bounds__(256, 2) void gemm_oproj(
    const u16* __restrict__ A, const u16* __restrict__ Bt,
    const float* __restrict__ bO, float* __restrict__ out) {
  __shared__ __align__(16) u16 lat[2][96 * 64];   // 24 KB
  __shared__ __align__(16) u16 lbt[2][64 * 64];   // 16 KB
  const int tid = threadIdx.x, lane = tid & 63, w = tid >> 6;
  const int wr = w >> 1, wc = w & 1;
  const int m0 = blockIdx.y * 96, n0 = blockIdx.x * 64;
  f32x4 acc[3][2] = {};
#define OSTAGE(buf, k0)                                                        \
  do {                                                                         \
    _Pragma("unroll")                                                          \
    for (int i = 0; i < 3; ++i) {                                              \
      int ch = tid + 256 * i;                                                  \
      int row = ch >> 3, pc = ch & 7;                                          \
      int kk = (k0) + ((pc ^ (row & 7)) << 3);                                 \
      gload_lds16(A + (size_t)(m0 + row) * DMODEL + kk, lat[buf] + (size_t)ch * 8); \
    }                                                                          \
    _Pragma("unroll")                                                          \
    for (int i = 0; i < 2; ++i) {                                              \
      int ch = tid + 256 * i;                                                  \
      int row = ch >> 3, pc = ch & 7;                                          \
      int kk = (k0) + ((pc ^ (row & 7)) << 3);                                 \
      gload_lds16(Bt + (size_t)(n0 + row) * DMODEL + kk, lbt[buf] + (size_t)ch * 8); \
    }                                                                          \
  } while (0)

  OSTAGE(0, 0);
  __syncthreads();
  int cur = 0;
  for (int kt = 0; kt < 8; ++kt) {
    const int nxt = cur ^ 1;
    if (kt < 7) {
      OSTAGE(nxt, (kt + 1) * 64);
      asm volatile("s_waitcnt vmcnt(5)" ::: "memory");
    } else {
      asm volatile("s_waitcnt vmcnt(0)" ::: "memory");
    }
    __builtin_amdgcn_s_barrier();
    #pragma unroll
    for (int ks = 0; ks < 2; ++ks) {
      bf16x8 af[3], bfr[2];
      const int cc = ks * 4 + (lane >> 4);
      #pragma unroll
      for (int f = 0; f < 3; ++f) {
        int ra = wr * 48 + f * 16 + (lane & 15);
        af[f]  = ld_bf8(lat[cur] + ra * 64 + ((cc ^ (ra & 7)) << 3));
      }
      #pragma unroll
      for (int f = 0; f < 2; ++f) {
        int rb = wc * 32 + f * 16 + (lane & 15);
        bfr[f] = ld_bf8(lbt[cur] + rb * 64 + ((cc ^ (rb & 7)) << 3));
      }
      __builtin_amdgcn_s_setprio(1);
      #pragma unroll
      for (int fr = 0; fr < 3; ++fr)
        #pragma unroll
        for (int fc = 0; fc < 2; ++fc)
          acc[fr][fc] = mfma16(af[fr], bfr[fc], acc[fr][fc]);
      __builtin_amdgcn_s_setprio(0);
    }
    __builtin_amdgcn_s_barrier();
    cur = nxt;
  }
  #pragma unroll
  for (int fr = 0; fr < 3; ++fr) {
    const int mbase = m0 + wr * 48 + fr * 16 + ((lane >> 4) << 2);
    #pragma unroll
    for (int fc = 0; fc < 2; ++fc) {
      const int col = n0 + wc * 32 + fc * 16 + (lane & 15);
      const float bias = bO[col];
      float* dst = out + (size_t)mbase * DMODEL + col;
      #pragma unroll
      for (int r = 0; r < 4; ++r) dst[(size_t)r * DMODEL] = acc[fr][fc][r] + bias;
    }
  }
#undef OSTAGE
}

// ------------------------------------------------------------ attention v15
// = v14 compute with 4-buffer ring, 2-in-flight staging, ONE arrival barrier
// per kt. Race audit: at iter t STAGE writes buf[(t+2)%4]; slowest reader
// (<=1 barrier behind) reads buf[(t-1)%4] (dist 3) or buf[t%4] (dist 2) —
// disjoint. vmcnt(4) after STAGE(t+2) => stage(t+1) landed pre-barrier;
// buf[t] was guaranteed one iteration earlier. t>=10: vmcnt(0).
// LDS 140 KB (1 block/CU — grid is 1/CU regardless).
__global__ __launch_bounds__(768, 3) void attn_kernel(
    const u16* __restrict__ Q, const u16* __restrict__ K,
    const u16* __restrict__ Vt, const float* __restrict__ table,
    u16* __restrict__ O) {
  // carve: [0,12288) bias | [12288,77824) kbuf 2hf x 4buf x 8KB | [77824,143360) vbuf
  __shared__ __align__(16) char smem[143360];
  u16* rb2k = (u16*)smem;
  const int tid = threadIdx.x, lane = tid & 63, w = tid >> 6;
  const int bid = blockIdx.x;
  const int xcd = bid & 7, idx = bid >> 3;
  const int bh  = xcd * 4 + (idx & 3);
  const int qt  = idx >> 2;
  const int h   = bh & (NHEAD - 1);
  for (int t = tid; t < 2 * 3072; t += 768) {
    const int c = (t >= 3072) ? 1 : 0;
    const int x = t - c * 3072;
    int src = 2558 - (x + c);
    src = src < 0 ? 0 : (src > 2046 ? 2046 : src);
    rb2k[c * 3072 + x] = f2bf(table[(size_t)src * NHEAD + h] * 1.4426950408889634f);
  }

  const int lo32 = lane & 31, hi = lane >> 5;
  const int ws = (w < 6) ? w : (w - 6);
  const int hf = (w < 6) ? 0 : 1;
  const int kbase = hf * 768;
  const int q  = qt * 192 + ws * 32 + lo32;
  const u16* Qb = Q  + (size_t)bh * NSEQ * HD;
  const u16* Kb = K  + (size_t)bh * NSEQ * HD;
  const u16* Vb = Vt + (size_t)bh * HD * NSEQ;

  const int tloc = tid - hf * 384;
  u16* kl0 = (u16*)(smem + 12288) + hf * 4 * 4096;
  u16* vl0 = (u16*)(smem + 77824) + hf * 4 * 4096;
#define STAGE(b, k0loc)                                                       \
  if (tloc < 256) {                                                           \
    _Pragma("unroll")                                                         \
    for (int i = 0; i < 2; ++i) {                                             \
      int ch = tloc + 256 * i;                                                \
      int row = ch >> 3, pc = ch & 7;                                         \
      int col = (pc ^ (row & 7)) << 3;                                        \
      gload_lds16(Kb + (size_t)(kbase + (k0loc) + row) * HD + col,            \
                  kl0 + (size_t)(b) * 4096 + ch * 8);                         \
      gload_lds16(Vb + (size_t)row * NSEQ + kbase + (k0loc) + col,            \
                  vl0 + (size_t)(b) * 4096 + ch * 8);                         \
    }                                                                         \
  }

  bf16x8 qf[4];
  #pragma unroll
  for (int ds = 0; ds < 4; ++ds)
    qf[ds] = ld_bf8(Qb + (size_t)q * HD + ds * 16 + hi * 8);

  float l_part = 0.f;
  f32x16 acc[2] = {};

  const int rswz = lo32 & 7;
  const int T0  = 1535 - q + 4 * hi + kbase;
  const int c2  = T0 & 1;
  const int dwb = (T0 - c2) >> 1;
  const uint32_t* rbp32 = (const uint32_t*)(rb2k + c2 * 3072);
  const float c1 = 0.125f * 1.4426950408889634f;

  STAGE(0, 0);
  STAGE(1, 64);
  __syncthreads();                       // drains both prologue stages + bias

  for (int kt = 0; kt < 12; ++kt) {
    if (kt <= 9) {
      STAGE((kt + 2) & 3, (kt + 2) * 64);
      asm volatile("s_waitcnt vmcnt(4)" ::: "memory");
    } else {
      asm volatile("s_waitcnt vmcnt(0)" ::: "memory");
    }
    __builtin_amdgcn_s_barrier();        // single arrival barrier per kt
    const u16* kb = kl0 + (kt & 3) * 4096;
    const u16* vb = vl0 + (kt & 3) * 4096;
    #pragma unroll
    for (int ktile = 0; ktile < 2; ++ktile) {
      f32x16 st = {};
      __builtin_amdgcn_s_setprio(1);
      #pragma unroll
      for (int ds = 0; ds < 4; ++ds) {
        const int row = ktile * 32 + lo32;
        const bf16x8 kf = ld_bf8(kb + row * 64 + (((2 * ds + hi) ^ rswz) << 3));
        st = mfma32(kf, qf[ds], st);
      }
      __builtin_amdgcn_s_setprio(0);
      const int dwk = dwb + ((kt * 64 + ktile * 32) >> 1);
      float bv[4][4];
      #pragma unroll
      for (int gp = 0; gp < 4; ++gp) {
        const uint32_t u0 = rbp32[dwk + 4 * gp];
        const uint32_t u1 = rbp32[dwk + 4 * gp + 1];
        bv[gp][0] = bflo(u0); bv[gp][1] = bfhi(u0);
        bv[gp][2] = bflo(u1); bv[gp][3] = bfhi(u1);
      }
      #pragma unroll
      for (int r = 0; r < 16; ++r) {
        float p = exp2_raw(__builtin_fmaf(st[r], c1, bv[r >> 2][r & 3]));
        st[r] = p;
        l_part += p;
      }
      uint32_t wv[8];
      #pragma unroll
      for (int i = 0; i < 8; ++i) wv[i] = pkbf(st[2 * i], st[2 * i + 1]);
      plswap(wv[0], wv[2], hi);  plswap(wv[1], wv[3], hi);
      plswap(wv[4], wv[6], hi);  plswap(wv[5], wv[7], hi);
      i32x4 b0; b0[0] = (int)wv[0]; b0[1] = (int)wv[1]; b0[2] = (int)wv[2]; b0[3] = (int)wv[3];
      i32x4 b1; b1[0] = (int)wv[4]; b1[1] = (int)wv[5]; b1[2] = (int)wv[6]; b1[3] = (int)wv[7];
      const bf16x8 pb0 = __builtin_bit_cast(bf16x8, b0);
      const bf16x8 pb1 = __builtin_bit_cast(bf16x8, b1);
      __builtin_amdgcn_s_setprio(1);
      #pragma unroll
      for (int dh = 0; dh < 2; ++dh) {
        const int vrow = dh * 32 + lo32;
        const bf16x8 va0 = ld_bf8(vb + vrow * 64 + (((4 * ktile + 0 + hi) ^ rswz) << 3));
        acc[dh] = mfma32(va0, pb0, acc[dh]);
        const bf16x8 va1 = ld_bf8(vb + vrow * 64 + (((4 * ktile + 2 + hi) ^ rswz) << 3));
        acc[dh] = mfma32(va1, pb1, acc[dh]);
      }
      __builtin_amdgcn_s_setprio(0);
    }
  }
  // ---- combine halves (additive partials); scratch = dead k/v buffers
  float* scr = (float*)(smem + 12288);
  __syncthreads();                       // all reads done before scratch reuse
  if (hf == 1) {
    float* wb = scr + ws * 2112;
    #pragma unroll
    for (int dh = 0; dh < 2; ++dh)
      #pragma unroll
      for (int i = 0; i < 4; ++i) {
        f32x4 c4; c4[0] = acc[dh][4*i]; c4[1] = acc[dh][4*i+1];
        c4[2] = acc[dh][4*i+2]; c4[3] = acc[dh][4*i+3];
        ((f32x4*)wb)[(dh * 4 + i) * 64 + lane] = c4;
      }
    wb[2048 + lane] = l_part;
  }
  __syncthreads();
  if (hf == 0) {
    const float* rb = scr + ws * 2112;
    #pragma unroll
    for (int dh = 0; dh < 2; ++dh)
      #pragma unroll
      for (int i = 0; i < 4; ++i) {
        const f32x4 c4 = ((const f32x4*)rb)[(dh * 4 + i) * 64 + lane];
        acc[dh][4*i] += c4[0]; acc[dh][4*i+1] += c4[1];
        acc[dh][4*i+2] += c4[2]; acc[dh][4*i+3] += c4[3];
      }
    l_part += rb[2048 + lane];
    float l_r = l_part + __shfl_xor(l_part, 32);
    const float inv = 1.0f / l_r;
    const int b = bh >> 3;
    u16* orow = O + ((size_t)(b * NSEQ + q)) * DMODEL + h * HD;
    #pragma unroll
    for (int dh = 0; dh < 2; ++dh)
      #pragma unroll
      for (int gp = 0; gp < 4; ++gp) {
        uint2 o4;
        o4.x = pkbf(acc[dh][4*gp]   * inv, acc[dh][4*gp+1] * inv);
        o4.y = pkbf(acc[dh][4*gp+2] * inv, acc[dh][4*gp+3] * inv);
        *(uint2*)(orow + dh * 32 + 8 * gp + 4 * hi) = o4;
      }
  }
#undef STAGE
}

// ---------------------------------------------------------------- launch
extern "C" void kernel_launch(void* const* d_in, const int* in_sizes, int n_in,
                              void* d_out, int out_size, void* d_ws, size_t ws_size,
                              hipStream_t stream) {
  const float* vis   = (const float*)d_in[0];
  const float* txt   = (const float*)d_in[1];
  const float* WQ    = (const float*)d_in[2];
  const float* bQ    = (const float*)d_in[3];
  const float* WK    = (const float*)d_in[4];
  const float* bK    = (const float*)d_in[5];
  const float* WV    = (const float*)d_in[6];
  const float* bV    = (const float*)d_in[7];
  const float* WO    = (const float*)d_in[8];
  const float* bO    = (const float*)d_in[9];
  const float* table = (const float*)d_in[10];
  const float* gamma = (const float*)d_in[11];
  const float* beta  = (const float*)d_in[12];
  float* out = (float*)d_out;

  char* p = (char*)d_ws;
  u16* zn    = (u16*)p; p += (size_t)NM * DMODEL * 2;
  u16* wqkvt = (u16*)p; p += (size_t)3 * DMODEL * DMODEL * 2;
  u16* wot   = (u16*)p; p += (size_t)DMODEL * DMODEL * 2;
  u16* q     = (u16*)p; p += (size_t)NM * DMODEL * 2;
  u16* k     = (u16*)p; p += (size_t)NM * DMODEL * 2;
  u16* vt    = (u16*)p; p += (size_t)NM * DMODEL * 2;
  u16* o     = (u16*)p; p += (size_t)NM * DMODEL * 2;

  hipLaunchKernelGGL(prep_kernel, dim3(2560), dim3(256), 0, stream,
                     vis, txt, gamma, beta, WQ, WK, WV, WO, zn, wqkvt, wot);
  hipLaunchKernelGGL(gemm_qkv, dim3(16, 32), dim3(256), 0, stream,
                     zn, wqkvt, bQ, bK, bV, q, k, vt);
  hipLaunchKernelGGL(attn_kernel, dim3(256), dim3(768), 0, stream,
                     q, k, vt, table, o);
  hipLaunchKernelGGL(gemm_oproj, dim3(8, 64), dim3(256), 0, stream,
                     o, wot, bO, out);
}

// Round 18
// 72.300 us; speedup vs baseline: 1.2590x; 1.0070x over previous
//
#include <hip/hip_runtime.h>
#include <stdint.h>

#define NSEQ   1536
#define NBATCH 4
#define NM     (NBATCH * NSEQ)   // 6144
#define DMODEL 512
#define NHEAD  8
#define HD     64
#define TBLN   2047              // 2*1024-1

typedef __attribute__((ext_vector_type(4)))  float f32x4;
typedef __attribute__((ext_vector_type(16))) float f32x16;
typedef __attribute__((ext_vector_type(4)))  int   i32x4;
typedef __attribute__((ext_vector_type(2)))  unsigned u32x2;
typedef __attribute__((ext_vector_type(8)))  __bf16 bf16x8;
typedef unsigned short u16;

static_assert(sizeof(bf16x8) == 16, "bf16x8 must be 16B");

__device__ inline u16 f2bf(float f) {
  union { float f; uint32_t u; } v; v.f = f;
  uint32_t u = v.u;
  return (u16)((u + 0x7fffu + ((u >> 16) & 1u)) >> 16);   // RNE
}

__device__ inline bf16x8 ld_bf8(const u16* p) {
  i32x4 v = *(const i32x4*)p;
  return __builtin_bit_cast(bf16x8, v);
}

__device__ inline f32x4 mfma16(bf16x8 a, bf16x8 b, f32x4 c) {
  return __builtin_amdgcn_mfma_f32_16x16x32_bf16(a, b, c, 0, 0, 0);
}

__device__ inline f32x16 mfma32(bf16x8 a, bf16x8 b, f32x16 c) {
  return __builtin_amdgcn_mfma_f32_32x32x16_bf16(a, b, c, 0, 0, 0);
}

__device__ inline void gload_lds16(const void* g, void* l) {
  __builtin_amdgcn_global_load_lds(
      (__attribute__((address_space(1))) void*)(g),
      (__attribute__((address_space(3))) void*)(l), 16, 0, 0);
}

__device__ inline uint32_t pkbf(float a, float b) {
  uint32_t r;
  asm("v_cvt_pk_bf16_f32 %0, %1, %2" : "=v"(r) : "v"(a), "v"(b));
  return r;   // lo16 = bf16(a), hi16 = bf16(b)
}

// Exchange halves across the lane<32 / lane>=32 split between two words.
__device__ inline void plswap(uint32_t& a, uint32_t& b, int hi) {
#if __has_builtin(__builtin_amdgcn_permlane32_swap)
  u32x2 r = __builtin_amdgcn_permlane32_swap(a, b, false, false);
  a = r[0]; b = r[1];
#else
  const uint32_t as = (uint32_t)__shfl_xor((int)a, 32);
  const uint32_t bs = (uint32_t)__shfl_xor((int)b, 32);
  const uint32_t na = hi ? bs : a;   // [a_lo | b_lo]
  const uint32_t nb = hi ? b : as;   // [a_hi | b_hi]
  a = na; b = nb;
#endif
}

__device__ inline float exp2_raw(float x) {   // |x| small: no libm guards
  float r;
  asm("v_exp_f32 %0, %1" : "=v"(r) : "v"(x));
  return r;
}

__device__ inline float bfhi(uint32_t u) {
  union { uint32_t u; float f; } v; v.u = u & 0xffff0000u; return v.f;
}
__device__ inline float bflo(uint32_t u) {
  union { uint32_t u; float f; } v; v.u = u << 16; return v.f;
}

// ------------------------------------------- fused LayerNorm + W-transpose
// blocks [0,1536): LN rows (4/block). blocks [1536,2560): weight transpose.
__global__ __launch_bounds__(256) void prep_kernel(
    const float* __restrict__ vis, const float* __restrict__ txt,
    const float* __restrict__ gamma, const float* __restrict__ beta,
    const float* __restrict__ WQ, const float* __restrict__ WK,
    const float* __restrict__ WV, const float* __restrict__ WO,
    u16* __restrict__ zn, u16* __restrict__ wqkvt, u16* __restrict__ wot) {
  __shared__ float t[32][33];
  if (blockIdx.x < 1536) {
    const int lane = threadIdx.x & 63;
    const int row  = blockIdx.x * 4 + (threadIdx.x >> 6);
    const int b = row / NSEQ, n = row - b * NSEQ;
    const float* src = (n < 1024) ? (vis + ((size_t)b * 1024 + n) * DMODEL)
                                  : (txt + ((size_t)b * 512 + (n - 1024)) * DMODEL);
    const float4* s4 = (const float4*)src;
    float4 x0 = s4[lane], x1 = s4[lane + 64];
    float s = x0.x + x0.y + x0.z + x0.w + x1.x + x1.y + x1.z + x1.w;
    float q = x0.x*x0.x + x0.y*x0.y + x0.z*x0.z + x0.w*x0.w
            + x1.x*x1.x + x1.y*x1.y + x1.z*x1.z + x1.w*x1.w;
    #pragma unroll
    for (int m = 1; m < 64; m <<= 1) { s += __shfl_xor(s, m); q += __shfl_xor(q, m); }
    const float mean = s * (1.0f / 512.0f);
    const float var  = q * (1.0f / 512.0f) - mean * mean;
    const float rstd = rsqrtf(var + 1e-5f);
    const float4* g4 = (const float4*)gamma;
    const float4* b4 = (const float4*)beta;
    float4 g0 = g4[lane], g1 = g4[lane + 64], p0 = b4[lane], p1 = b4[lane + 64];
    u16* dst = zn + (size_t)row * DMODEL;
    ushort4 o0, o1;
    o0.x = f2bf((x0.x - mean) * rstd * g0.x + p0.x);
    o0.y = f2bf((x0.y - mean) * rstd * g0.y + p0.y);
    o0.z = f2bf((x0.z - mean) * rstd * g0.z + p0.z);
    o0.w = f2bf((x0.w - mean) * rstd * g0.w + p0.w);
    o1.x = f2bf((x1.x - mean) * rstd * g1.x + p1.x);
    o1.y = f2bf((x1.y - mean) * rstd * g1.y + p1.y);
    o1.z = f2bf((x1.z - mean) * rstd * g1.z + p1.z);
    o1.w = f2bf((x1.w - mean) * rstd * g1.w + p1.w);
    *(ushort4*)(dst + lane * 4)        = o0;
    *(ushort4*)(dst + (lane + 64) * 4) = o1;
  } else {
    const int id = blockIdx.x - 1536;             // [0,1024)
    const int m = id & 3;
    const int rem = id >> 2;                      // [0,256)
    const float* W = (m == 0) ? WQ : (m == 1) ? WK : (m == 2) ? WV : WO;
    const int n0 = (rem & 15) * 32, k0 = (rem >> 4) * 32;
    const int tx = threadIdx.x & 31, ty = threadIdx.x >> 5;
    #pragma unroll
    for (int j = 0; j < 4; ++j)
      t[ty + j * 8][tx] = W[(size_t)(k0 + ty + j * 8) * DMODEL + n0 + tx];
    __syncthreads();
    u16* out = (m < 3) ? (wqkvt + (size_t)m * DMODEL * DMODEL) : wot;
    #pragma unroll
    for (int j = 0; j < 4; ++j)
      out[(size_t)(n0 + ty + j * 8) * DMODEL + k0 + tx] = f2bf(t[tx][ty + j * 8]);
  }
}

// ------------------------------------------------------------- QKV GEMM v2
// 192(M) x 96(N) tile, BK=64, 4 waves (2x2), wave tile 96x48.
// grid 32x16 = 512 blocks = exactly 2/CU. Double-buffered LDS (72 KB),
// counted vmcnt(9) + two arrival barriers per kt.
__global__ __launch_bounds__(256, 2) void gemm_qkv(
    const u16* __restrict__ A, const u16* __restrict__ Bt,
    const float* __restrict__ bQ, const float* __restrict__ bK, const float* __restrict__ bV,
    u16* __restrict__ Q, u16* __restrict__ Kk, u16* __restrict__ Vt) {
  __shared__ __align__(16) u16 lat[2][192 * 64];  // 48 KB
  __shared__ __align__(16) u16 lbt[2][96 * 64];   // 24 KB
  const int tid = threadIdx.x, lane = tid & 63, w = tid >> 6;
  const int wr = w >> 1, wc = w & 1;
  const int m0 = blockIdx.y * 192, n0 = blockIdx.x * 96;
  f32x4 acc[6][3] = {};
#define QSTAGE(buf, k0)                                                        \
  do {                                                                         \
    _Pragma("unroll")                                                          \
    for (int i = 0; i < 6; ++i) {                                              \
      int ch = tid + 256 * i;                                                  \
      int row = ch >> 3, pc = ch & 7;                                          \
      int kk = (k0) + ((pc ^ (row & 7)) << 3);                                 \
      gload_lds16(A + (size_t)(m0 + row) * DMODEL + kk, lat[buf] + (size_t)ch * 8); \
    }                                                                          \
    _Pragma("unroll")                                                          \
    for (int i = 0; i < 3; ++i) {                                              \
      int ch = tid + 256 * i;                                                  \
      int row = ch >> 3, pc = ch & 7;                                          \
      int kk = (k0) + ((pc ^ (row & 7)) << 3);                                 \
      gload_lds16(Bt + (size_t)(n0 + row) * DMODEL + kk, lbt[buf] + (size_t)ch * 8); \
    }                                                                          \
  } while (0)

  QSTAGE(0, 0);
  __syncthreads();
  int cur = 0;
  for (int kt = 0; kt < 8; ++kt) {
    const int nxt = cur ^ 1;
    if (kt < 7) {
      QSTAGE(nxt, (kt + 1) * 64);
      asm volatile("s_waitcnt vmcnt(9)" ::: "memory");
    } else {
      asm volatile("s_waitcnt vmcnt(0)" ::: "memory");
    }
    __builtin_amdgcn_s_barrier();
    #pragma unroll
    for (int ks = 0; ks < 2; ++ks) {
      bf16x8 af[6], bfr[3];
      const int cc = ks * 4 + (lane >> 4);
      #pragma unroll
      for (int f = 0; f < 6; ++f) {
        int ra = wr * 96 + f * 16 + (lane & 15);
        af[f]  = ld_bf8(lat[cur] + ra * 64 + ((cc ^ (ra & 7)) << 3));
      }
      #pragma unroll
      for (int f = 0; f < 3; ++f) {
        int rb = wc * 48 + f * 16 + (lane & 15);
        bfr[f] = ld_bf8(lbt[cur] + rb * 64 + ((cc ^ (rb & 7)) << 3));
      }
      __builtin_amdgcn_s_setprio(1);
      #pragma unroll
      for (int fr = 0; fr < 6; ++fr)
        #pragma unroll
        for (int fc = 0; fc < 3; ++fc)
          acc[fr][fc] = mfma16(af[fr], bfr[fc], acc[fr][fc]);
      __builtin_amdgcn_s_setprio(0);
    }
    __builtin_amdgcn_s_barrier();
    cur = nxt;
  }
  #pragma unroll
  for (int fr = 0; fr < 6; ++fr) {
    const int mbase = m0 + wr * 96 + fr * 16 + ((lane >> 4) << 2);
    const int b = mbase / NSEQ;
    const int nseq = mbase - b * NSEQ;
    #pragma unroll
    for (int fc = 0; fc < 3; ++fc) {
      const int col = n0 + wc * 48 + fc * 16 + (lane & 15);
      const int which = col >> 9;
      const int cw = col & 511;
      const int h = cw >> 6, d = cw & 63;
      const float bias = (which == 0) ? bQ[cw] : (which == 1) ? bK[cw] : bV[cw];
      if (which < 2) {
        u16* dst = ((which == 0) ? Q : Kk) + ((size_t)(b * NHEAD + h) * NSEQ + nseq) * HD + d;
        #pragma unroll
        for (int r = 0; r < 4; ++r) dst[(size_t)r * HD] = f2bf(acc[fr][fc][r] + bias);
      } else {
        ushort4 pv;
        pv.x = f2bf(acc[fr][fc][0] + bias);
        pv.y = f2bf(acc[fr][fc][1] + bias);
        pv.z = f2bf(acc[fr][fc][2] + bias);
        pv.w = f2bf(acc[fr][fc][3] + bias);
        *(ushort4*)(Vt + ((size_t)(b * NHEAD + h) * HD + d) * NSEQ + nseq) = pv;
      }
    }
  }
#undef QSTAGE
}

// ------------------------------------------------------------ O-proj GEMM v2
__global__ __launch_bounds__(256, 2) void gemm_oproj(
    const u16* __restrict__ A, const u16* __restrict__ Bt,
    const float* __restrict__ bO, float* __restrict__ out) {
  __shared__ __align__(16) u16 lat[2][96 * 64];   // 24 KB
  __shared__ __align__(16) u16 lbt[2][64 * 64];   // 16 KB
  const int tid = threadIdx.x, lane = tid & 63, w = tid >> 6;
  const int wr = w >> 1, wc = w & 1;
  const int m0 = blockIdx.y * 96, n0 = blockIdx.x * 64;
  f32x4 acc[3][2] = {};
#define OSTAGE(buf, k0)                                                        \
  do {                                                                         \
    _Pragma("unroll")                                                          \
    for (int i = 0; i < 3; ++i) {                                              \
      int ch = tid + 256 * i;                                                  \
      int row = ch >> 3, pc = ch & 7;                                          \
      int kk = (k0) + ((pc ^ (row & 7)) << 3);                                 \
      gload_lds16(A + (size_t)(m0 + row) * DMODEL + kk, lat[buf] + (size_t)ch * 8); \
    }                                                                          \
    _Pragma("unroll")                                                          \
    for (int i = 0; i < 2; ++i) {                                              \
      int ch = tid + 256 * i;                                                  \
      int row = ch >> 3, pc = ch & 7;                                          \
      int kk = (k0) + ((pc ^ (row & 7)) << 3);                                 \
      gload_lds16(Bt + (size_t)(n0 + row) * DMODEL + kk, lbt[buf] + (size_t)ch * 8); \
    }                                                                          \
  } while (0)

  OSTAGE(0, 0);
  __syncthreads();
  int cur = 0;
  for (int kt = 0; kt < 8; ++kt) {
    const int nxt = cur ^ 1;
    if (kt < 7) {
      OSTAGE(nxt, (kt + 1) * 64);
      asm volatile("s_waitcnt vmcnt(5)" ::: "memory");
    } else {
      asm volatile("s_waitcnt vmcnt(0)" ::: "memory");
    }
    __builtin_amdgcn_s_barrier();
    #pragma unroll
    for (int ks = 0; ks < 2; ++ks) {
      bf16x8 af[3], bfr[2];
      const int cc = ks * 4 + (lane >> 4);
      #pragma unroll
      for (int f = 0; f < 3; ++f) {
        int ra = wr * 48 + f * 16 + (lane & 15);
        af[f]  = ld_bf8(lat[cur] + ra * 64 + ((cc ^ (ra & 7)) << 3));
      }
      #pragma unroll
      for (int f = 0; f < 2; ++f) {
        int rb = wc * 32 + f * 16 + (lane & 15);
        bfr[f] = ld_bf8(lbt[cur] + rb * 64 + ((cc ^ (rb & 7)) << 3));
      }
      __builtin_amdgcn_s_setprio(1);
      #pragma unroll
      for (int fr = 0; fr < 3; ++fr)
        #pragma unroll
        for (int fc = 0; fc < 2; ++fc)
          acc[fr][fc] = mfma16(af[fr], bfr[fc], acc[fr][fc]);
      __builtin_amdgcn_s_setprio(0);
    }
    __builtin_amdgcn_s_barrier();
    cur = nxt;
  }
  #pragma unroll
  for (int fr = 0; fr < 3; ++fr) {
    const int mbase = m0 + wr * 48 + fr * 16 + ((lane >> 4) << 2);
    #pragma unroll
    for (int fc = 0; fc < 2; ++fc) {
      const int col = n0 + wc * 32 + fc * 16 + (lane & 15);
      const float bias = bO[col];
      float* dst = out + (size_t)mbase * DMODEL + col;
      #pragma unroll
      for (int r = 0; r < 4; ++r) dst[(size_t)r * DMODEL] = acc[fr][fc][r] + bias;
    }
  }
#undef OSTAGE
}

// ------------------------------------------------------------ attention v15
// (validated R16): 32x32 MFMA, swapped QK^T, in-register P via cvt_pk +
// permlane32_swap, TWO d-half accumulators, 12 waves = 6 q-tiles x 2 k-halves
// with additive no-max partials; 4-buffer ring, 2-in-flight staging, ONE
// arrival barrier per kt (counted vmcnt(4)).
__global__ __launch_bounds__(768, 3) void attn_kernel(
    const u16* __restrict__ Q, const u16* __restrict__ K,
    const u16* __restrict__ Vt, const float* __restrict__ table,
    u16* __restrict__ O) {
  // carve: [0,12288) bias | [12288,77824) kbuf 2hf x 4buf x 8KB | [77824,143360) vbuf
  __shared__ __align__(16) char smem[143360];
  u16* rb2k = (u16*)smem;
  const int tid = threadIdx.x, lane = tid & 63, w = tid >> 6;
  const int bid = blockIdx.x;
  const int xcd = bid & 7, idx = bid >> 3;
  const int bh  = xcd * 4 + (idx & 3);
  const int qt  = idx >> 2;
  const int h   = bh & (NHEAD - 1);
  for (int t = tid; t < 2 * 3072; t += 768) {
    const int c = (t >= 3072) ? 1 : 0;
    const int x = t - c * 3072;
    int src = 2558 - (x + c);
    src = src < 0 ? 0 : (src > 2046 ? 2046 : src);
    rb2k[c * 3072 + x] = f2bf(table[(size_t)src * NHEAD + h] * 1.4426950408889634f);
  }

  const int lo32 = lane & 31, hi = lane >> 5;
  const int ws = (w < 6) ? w : (w - 6);
  const int hf = (w < 6) ? 0 : 1;
  const int kbase = hf * 768;
  const int q  = qt * 192 + ws * 32 + lo32;
  const u16* Qb = Q  + (size_t)bh * NSEQ * HD;
  const u16* Kb = K  + (size_t)bh * NSEQ * HD;
  const u16* Vb = Vt + (size_t)bh * HD * NSEQ;

  const int tloc = tid - hf * 384;
  u16* kl0 = (u16*)(smem + 12288) + hf * 4 * 4096;
  u16* vl0 = (u16*)(smem + 77824) + hf * 4 * 4096;
#define STAGE(b, k0loc)                                                       \
  if (tloc < 256) {                                                           \
    _Pragma("unroll")                                                         \
    for (int i = 0; i < 2; ++i) {                                             \
      int ch = tloc + 256 * i;                                                \
      int row = ch >> 3, pc = ch & 7;                                         \
      int col = (pc ^ (row & 7)) << 3;                                        \
      gload_lds16(Kb + (size_t)(kbase + (k0loc) + row) * HD + col,            \
                  kl0 + (size_t)(b) * 4096 + ch * 8);                         \
      gload_lds16(Vb + (size_t)row * NSEQ + kbase + (k0loc) + col,            \
                  vl0 + (size_t)(b) * 4096 + ch * 8);                         \
    }                                                                         \
  }

  bf16x8 qf[4];
  #pragma unroll
  for (int ds = 0; ds < 4; ++ds)
    qf[ds] = ld_bf8(Qb + (size_t)q * HD + ds * 16 + hi * 8);

  float l_part = 0.f;
  f32x16 acc[2] = {};

  const int rswz = lo32 & 7;
  const int T0  = 1535 - q + 4 * hi + kbase;
  const int c2  = T0 & 1;
  const int dwb = (T0 - c2) >> 1;
  const uint32_t* rbp32 = (const uint32_t*)(rb2k + c2 * 3072);
  const float c1 = 0.125f * 1.4426950408889634f;

  STAGE(0, 0);
  STAGE(1, 64);
  __syncthreads();                       // drains both prologue stages + bias

  for (int kt = 0; kt < 12; ++kt) {
    if (kt <= 9) {
      STAGE((kt + 2) & 3, (kt + 2) * 64);
      asm volatile("s_waitcnt vmcnt(4)" ::: "memory");
    } else {
      asm volatile("s_waitcnt vmcnt(0)" ::: "memory");
    }
    __builtin_amdgcn_s_barrier();        // single arrival barrier per kt
    const u16* kb = kl0 + (kt & 3) * 4096;
    const u16* vb = vl0 + (kt & 3) * 4096;
    #pragma unroll
    for (int ktile = 0; ktile < 2; ++ktile) {
      f32x16 st = {};
      __builtin_amdgcn_s_setprio(1);
      #pragma unroll
      for (int ds = 0; ds < 4; ++ds) {
        const int row = ktile * 32 + lo32;
        const bf16x8 kf = ld_bf8(kb + row * 64 + (((2 * ds + hi) ^ rswz) << 3));
        st = mfma32(kf, qf[ds], st);
      }
      __builtin_amdgcn_s_setprio(0);
      const int dwk = dwb + ((kt * 64 + ktile * 32) >> 1);
      float bv[4][4];
      #pragma unroll
      for (int gp = 0; gp < 4; ++gp) {
        const uint32_t u0 = rbp32[dwk + 4 * gp];
        const uint32_t u1 = rbp32[dwk + 4 * gp + 1];
        bv[gp][0] = bflo(u0); bv[gp][1] = bfhi(u0);
        bv[gp][2] = bflo(u1); bv[gp][3] = bfhi(u1);
      }
      #pragma unroll
      for (int r = 0; r < 16; ++r) {
        float p = exp2_raw(__builtin_fmaf(st[r], c1, bv[r >> 2][r & 3]));
        st[r] = p;
        l_part += p;
      }
      uint32_t wv[8];
      #pragma unroll
      for (int i = 0; i < 8; ++i) wv[i] = pkbf(st[2 * i], st[2 * i + 1]);
      plswap(wv[0], wv[2], hi);  plswap(wv[1], wv[3], hi);
      plswap(wv[4], wv[6], hi);  plswap(wv[5], wv[7], hi);
      i32x4 b0; b0[0] = (int)wv[0]; b0[1] = (int)wv[1]; b0[2] = (int)wv[2]; b0[3] = (int)wv[3];
      i32x4 b1; b1[0] = (int)wv[4]; b1[1] = (int)wv[5]; b1[2] = (int)wv[6]; b1[3] = (int)wv[7];
      const bf16x8 pb0 = __builtin_bit_cast(bf16x8, b0);
      const bf16x8 pb1 = __builtin_bit_cast(bf16x8, b1);
      __builtin_amdgcn_s_setprio(1);
      #pragma unroll
      for (int dh = 0; dh < 2; ++dh) {
        const int vrow = dh * 32 + lo32;
        const bf16x8 va0 = ld_bf8(vb + vrow * 64 + (((4 * ktile + 0 + hi) ^ rswz) << 3));
        acc[dh] = mfma32(va0, pb0, acc[dh]);
        const bf16x8 va1 = ld_bf8(vb + vrow * 64 + (((4 * ktile + 2 + hi) ^ rswz) << 3));
        acc[dh] = mfma32(va1, pb1, acc[dh]);
      }
      __builtin_amdgcn_s_setprio(0);
    }
  }
  // ---- combine halves (additive partials); scratch = dead k/v buffers
  float* scr = (float*)(smem + 12288);
  __syncthreads();                       // all reads done before scratch reuse
  if (hf == 1) {
    float* wb = scr + ws * 2112;
    #pragma unroll
    for (int dh = 0; dh < 2; ++dh)
      #pragma unroll
      for (int i = 0; i < 4; ++i) {
        f32x4 c4; c4[0] = acc[dh][4*i]; c4[1] = acc[dh][4*i+1];
        c4[2] = acc[dh][4*i+2]; c4[3] = acc[dh][4*i+3];
        ((f32x4*)wb)[(dh * 4 + i) * 64 + lane] = c4;
      }
    wb[2048 + lane] = l_part;
  }
  __syncthreads();
  if (hf == 0) {
    const float* rb = scr + ws * 2112;
    #pragma unroll
    for (int dh = 0; dh < 2; ++dh)
      #pragma unroll
      for (int i = 0; i < 4; ++i) {
        const f32x4 c4 = ((const f32x4*)rb)[(dh * 4 + i) * 64 + lane];
        acc[dh][4*i] += c4[0]; acc[dh][4*i+1] += c4[1];
        acc[dh][4*i+2] += c4[2]; acc[dh][4*i+3] += c4[3];
      }
    l_part += rb[2048 + lane];
    float l_r = l_part + __shfl_xor(l_part, 32);
    const float inv = 1.0f / l_r;
    const int b = bh >> 3;
    u16* orow = O + ((size_t)(b * NSEQ + q)) * DMODEL + h * HD;
    #pragma unroll
    for (int dh = 0; dh < 2; ++dh)
      #pragma unroll
      for (int gp = 0; gp < 4; ++gp) {
        uint2 o4;
        o4.x = pkbf(acc[dh][4*gp]   * inv, acc[dh][4*gp+1] * inv);
        o4.y = pkbf(acc[dh][4*gp+2] * inv, acc[dh][4*gp+3] * inv);
        *(uint2*)(orow + dh * 32 + 8 * gp + 4 * hi) = o4;
      }
  }
#undef STAGE
}

// ---------------------------------------------------------------- launch
extern "C" void kernel_launch(void* const* d_in, const int* in_sizes, int n_in,
                              void* d_out, int out_size, void* d_ws, size_t ws_size,
                              hipStream_t stream) {
  const float* vis   = (const float*)d_in[0];
  const float* txt   = (const float*)d_in[1];
  const float* WQ    = (const float*)d_in[2];
  const float* bQ    = (const float*)d_in[3];
  const float* WK    = (const float*)d_in[4];
  const float* bK    = (const float*)d_in[5];
  const float* WV    = (const float*)d_in[6];
  const float* bV    = (const float*)d_in[7];
  const float* WO    = (const float*)d_in[8];
  const float* bO    = (const float*)d_in[9];
  const float* table = (const float*)d_in[10];
  const float* gamma = (const float*)d_in[11];
  const float* beta  = (const float*)d_in[12];
  float* out = (float*)d_out;

  char* p = (char*)d_ws;
  u16* zn    = (u16*)p; p += (size_t)NM * DMODEL * 2;
  u16* wqkvt = (u16*)p; p += (size_t)3 * DMODEL * DMODEL * 2;
  u16* wot   = (u16*)p; p += (size_t)DMODEL * DMODEL * 2;
  u16* q     = (u16*)p; p += (size_t)NM * DMODEL * 2;
  u16* k     = (u16*)p; p += (size_t)NM * DMODEL * 2;
  u16* vt    = (u16*)p; p += (size_t)NM * DMODEL * 2;
  u16* o     = (u16*)p; p += (size_t)NM * DMODEL * 2;

  hipLaunchKernelGGL(prep_kernel, dim3(2560), dim3(256), 0, stream,
                     vis, txt, gamma, beta, WQ, WK, WV, WO, zn, wqkvt, wot);
  hipLaunchKernelGGL(gemm_qkv, dim3(16, 32), dim3(256), 0, stream,
                     zn, wqkvt, bQ, bK, bV, q, k, vt);
  hipLaunchKernelGGL(attn_kernel, dim3(256), dim3(768), 0, stream,
                     q, k, vt, table, o);
  hipLaunchKernelGGL(gemm_oproj, dim3(8, 64), dim3(256), 0, stream,
                     o, wot, bO, out);
}